// Round 10
// baseline (2317.696 us; speedup 1.0000x reference)
//
#include <hip/hip_runtime.h>
#include <math.h>

#define WW 32
#define FF 16
#define HH 64

typedef __attribute__((ext_vector_type(8))) short bf16x8;
typedef __attribute__((ext_vector_type(4))) float f32x4;

__device__ __forceinline__ unsigned short bf16h(float f) {   // RNE round
    unsigned int u = __float_as_uint(f);
    unsigned int r = (u + 0x7FFFu + ((u >> 16) & 1u)) >> 16;
    return (unsigned short)r;
}
__device__ __forceinline__ float fsig(float v)  { return __fdividef(1.0f, 1.0f + __expf(-v)); }
__device__ __forceinline__ float ftanh(float v) { return 1.0f - __fdividef(2.0f, 1.0f + __expf(2.0f * v)); }

// trunc-split: hi = trunc-bf16(v), lo = trunc-bf16(v - hi)
__device__ __forceinline__ void tsplit8(const float* v, bf16x8& hi, bf16x8& lo) {
    #pragma unroll
    for (int i = 0; i < 8; i++) {
        unsigned int u = __float_as_uint(v[i]);
        hi[i] = (short)(u >> 16);
        float lf = v[i] - __uint_as_float(u & 0xFFFF0000u);
        lo[i] = (short)(__float_as_uint(lf) >> 16);
    }
}

// ---------------- LSTM via MFMA (R8 kernel, proven 838us, no spill) ----------------
__global__ __launch_bounds__(256, 2) void lstm_mfma_kernel(
    const float* __restrict__ x,      // [N,32,16]
    const float* __restrict__ W_ih,   // [256,16]
    const float* __restrict__ W_hh,   // [256,64]
    const float* __restrict__ b_ih,   // [256]
    const float* __restrict__ b_hh,   // [256]
    float* __restrict__ h_out,        // [N,64]
    int nN)
{
    __shared__ short Zs[2][2][64][64];   // 32768 B
    __shared__ short Xs[2][64][32];      // 8192 B : [node][xh(16)|xl(16)]
    const int tid  = threadIdx.x;
    const int lane = tid & 63;
    const int wv   = tid >> 6;
    const int l15  = lane & 15;
    const int g    = lane >> 4;
    const int n0   = blockIdx.x * 64;

    bf16x8 Bh[4][2], Bl[4][2], Bx[4];
    float bias[4];
    #pragma unroll
    for (int gate = 0; gate < 4; gate++) {
        const int j = 64 * gate + 16 * wv + l15;
        bias[gate] = b_ih[j] + b_hh[j];
        #pragma unroll
        for (int q = 0; q < 2; q++) {
            const float* wr = W_hh + j * HH + 32 * q + 8 * g;
            float v[8];
            float4 a = reinterpret_cast<const float4*>(wr)[0];
            float4 b = reinterpret_cast<const float4*>(wr)[1];
            v[0]=a.x; v[1]=a.y; v[2]=a.z; v[3]=a.w; v[4]=b.x; v[5]=b.y; v[6]=b.z; v[7]=b.w;
            tsplit8(v, Bh[gate][q], Bl[gate][q]);
        }
        {
            const float* wr = W_ih + j * FF + 8 * (g & 1);
            float4 a = reinterpret_cast<const float4*>(wr)[0];
            float4 b = reinterpret_cast<const float4*>(wr)[1];
            float v[8] = {a.x,a.y,a.z,a.w,b.x,b.y,b.z,b.w};
            bf16x8 bx;
            #pragma unroll
            for (int i = 0; i < 8; i++) bx[i] = (short)bf16h(v[i]);
            Bx[gate] = bx;
        }
    }

    {
        int4* zz = (int4*)(&Zs[0][0][0][0]);
        #pragma unroll
        for (int c = 0; c < 4; c++) zz[c * 256 + tid] = make_int4(0, 0, 0, 0);
        int gn = n0 + (tid >> 2); if (gn >= nN) gn = nN - 1;
        const float4 xf = *reinterpret_cast<const float4*>(x + (size_t)gn * (WW * FF) + (tid & 3) * 4);
        unsigned int u0 = __float_as_uint(xf.x), u1 = __float_as_uint(xf.y);
        unsigned int u2 = __float_as_uint(xf.z), u3 = __float_as_uint(xf.w);
        short4 hs = make_short4((short)(u0>>16), (short)(u1>>16), (short)(u2>>16), (short)(u3>>16));
        float f0 = xf.x - __uint_as_float(u0 & 0xFFFF0000u);
        float f1 = xf.y - __uint_as_float(u1 & 0xFFFF0000u);
        float f2 = xf.z - __uint_as_float(u2 & 0xFFFF0000u);
        float f3 = xf.w - __uint_as_float(u3 & 0xFFFF0000u);
        short4 ls = make_short4((short)(__float_as_uint(f0)>>16), (short)(__float_as_uint(f1)>>16),
                                (short)(__float_as_uint(f2)>>16), (short)(__float_as_uint(f3)>>16));
        *reinterpret_cast<short4*>(&Xs[0][tid >> 2][(tid & 3) * 4])      = hs;
        *reinterpret_cast<short4*>(&Xs[0][tid >> 2][16 + (tid & 3) * 4]) = ls;
    }
    __syncthreads();

    const char* zbase  = (const char*)Zs;
    char*       zwbase = (char*)Zs;
    const char* xbase  = (const char*)Xs;

    const int aoff0 = l15 * 128 + ((g ^ (l15 & 7)) * 16);
    const int aoff1 = l15 * 128 + (((4 + g) ^ (l15 & 7)) * 16);
    const int xoff  = l15 * 64 + g * 16;
    const int wblk  = 2 * wv + (l15 >> 3);
    const int wsh   = (l15 & 7) * 2;

    f32x4 cst[4] = {{0.f,0.f,0.f,0.f},{0.f,0.f,0.f,0.f},{0.f,0.f,0.f,0.f},{0.f,0.f,0.f,0.f}};

    #pragma unroll 1
    for (int t = 0; t < WW; t++) {
        const int buf = t & 1;

        int gn = n0 + (tid >> 2); if (gn >= nN) gn = nN - 1;
        const int tn = (t + 1 < WW) ? (t + 1) : t;
        const float4 xf = *reinterpret_cast<const float4*>(x + (size_t)gn * (WW * FF) + tn * FF + (tid & 3) * 4);

        #pragma unroll
        for (int rt = 0; rt < 4; rt++) {
            const bf16x8 Ah0 = *reinterpret_cast<const bf16x8*>(zbase + buf*16384 + 0*8192 + rt*2048 + aoff0);
            const bf16x8 Ah1 = *reinterpret_cast<const bf16x8*>(zbase + buf*16384 + 0*8192 + rt*2048 + aoff1);
            const bf16x8 Al0 = *reinterpret_cast<const bf16x8*>(zbase + buf*16384 + 1*8192 + rt*2048 + aoff0);
            const bf16x8 Al1 = *reinterpret_cast<const bf16x8*>(zbase + buf*16384 + 1*8192 + rt*2048 + aoff1);
            const bf16x8 Ax  = *reinterpret_cast<const bf16x8*>(xbase + buf*4096 + rt*1024 + xoff);
            f32x4 acc[4];
            #pragma unroll
            for (int gate = 0; gate < 4; gate++) {
                f32x4 ini = {bias[gate], bias[gate], bias[gate], bias[gate]};
                acc[gate] = ini;
            }
            #pragma unroll
            for (int gate = 0; gate < 4; gate++) {
                acc[gate] = __builtin_amdgcn_mfma_f32_16x16x32_bf16(Ah0, Bh[gate][0], acc[gate], 0, 0, 0);
                acc[gate] = __builtin_amdgcn_mfma_f32_16x16x32_bf16(Al0, Bh[gate][0], acc[gate], 0, 0, 0);
                acc[gate] = __builtin_amdgcn_mfma_f32_16x16x32_bf16(Ah0, Bl[gate][0], acc[gate], 0, 0, 0);
                acc[gate] = __builtin_amdgcn_mfma_f32_16x16x32_bf16(Ah1, Bh[gate][1], acc[gate], 0, 0, 0);
                acc[gate] = __builtin_amdgcn_mfma_f32_16x16x32_bf16(Al1, Bh[gate][1], acc[gate], 0, 0, 0);
                acc[gate] = __builtin_amdgcn_mfma_f32_16x16x32_bf16(Ah1, Bl[gate][1], acc[gate], 0, 0, 0);
                acc[gate] = __builtin_amdgcn_mfma_f32_16x16x32_bf16(Ax,  Bx[gate],    acc[gate], 0, 0, 0);
            }
            #pragma unroll
            for (int r = 0; r < 4; r++) {
                const float ig = fsig(acc[0][r]);
                const float fg = fsig(acc[1][r]);
                const float gg = ftanh(acc[2][r]);
                const float og = fsig(acc[3][r]);
                const float c  = fg * cst[rt][r] + ig * gg;
                cst[rt][r] = c;
                const float h  = og * ftanh(c);
                if (t < WW - 1) {
                    const int node = 16 * rt + 4 * g + r;
                    const int sw   = ((wblk ^ ((4 * g + r) & 7)) * 16) + wsh;
                    char* wp = zwbase + (buf ^ 1) * 16384 + node * 128 + sw;
                    unsigned int u = __float_as_uint(h);
                    *(short*)(wp)        = (short)(u >> 16);
                    float lf = h - __uint_as_float(u & 0xFFFF0000u);
                    *(short*)(wp + 8192) = (short)(__float_as_uint(lf) >> 16);
                } else {
                    const int node = n0 + 16 * rt + 4 * g + r;
                    if (node < nN) h_out[(size_t)node * HH + 16 * wv + l15] = h;
                }
            }
        }
        if (t < WW - 1) {
            unsigned int u0 = __float_as_uint(xf.x), u1 = __float_as_uint(xf.y);
            unsigned int u2 = __float_as_uint(xf.z), u3 = __float_as_uint(xf.w);
            short4 hs = make_short4((short)(u0>>16), (short)(u1>>16), (short)(u2>>16), (short)(u3>>16));
            float f0 = xf.x - __uint_as_float(u0 & 0xFFFF0000u);
            float f1 = xf.y - __uint_as_float(u1 & 0xFFFF0000u);
            float f2 = xf.z - __uint_as_float(u2 & 0xFFFF0000u);
            float f3 = xf.w - __uint_as_float(u3 & 0xFFFF0000u);
            short4 ls = make_short4((short)(__float_as_uint(f0)>>16), (short)(__float_as_uint(f1)>>16),
                                    (short)(__float_as_uint(f2)>>16), (short)(__float_as_uint(f3)>>16));
            *reinterpret_cast<short4*>(&Xs[buf ^ 1][tid >> 2][(tid & 3) * 4])      = hs;
            *reinterpret_cast<short4*>(&Xs[buf ^ 1][tid >> 2][16 + (tid & 3) * 4]) = ls;
        }
        __syncthreads();
    }
}

// ---------------- CSR build ----------------
__global__ void deg_int_kernel(const int* __restrict__ dst, int* __restrict__ deg, int nE, int nN) {
    int e = blockIdx.x * 256 + threadIdx.x;
    if (e < nE) {
        int d = dst[e];
        if ((unsigned)d < (unsigned)nN) atomicAdd(&deg[d], 1);
    }
}

__global__ void dis_from_deg_kernel(const int* __restrict__ deg, float* __restrict__ dis, int nN) {
    int i = blockIdx.x * 256 + threadIdx.x;
    if (i < nN) dis[i] = rsqrtf((float)deg[i] + 1.0f);
}

// single-block scan: row_ptr/cursor = exclusive prefix of deg; also dis = rsqrt(deg+1)
__global__ __launch_bounds__(1024) void scan_kernel(const int* __restrict__ deg,
                                                    int* __restrict__ row_ptr,
                                                    int* __restrict__ cursor,
                                                    float* __restrict__ dis, int nN)
{
    __shared__ int part[1024];
    const int tid = threadIdx.x;
    const int chunk = (nN + 1023) / 1024;
    const int s = tid * chunk;
    const int e = min(s + chunk, nN);
    int sum = 0;
    for (int i = s; i < e; i++) sum += deg[i];
    part[tid] = sum;
    __syncthreads();
    if (tid == 0) {
        int acc = 0;
        for (int i = 0; i < 1024; i++) { int v = part[i]; part[i] = acc; acc += v; }
    }
    __syncthreads();
    int acc = part[tid];
    for (int i = s; i < e; i++) {
        const int d = deg[i];
        row_ptr[i] = acc;
        cursor[i]  = acc;
        dis[i]     = rsqrtf((float)d + 1.0f);
        acc += d;
    }
}

// pack (src, dis[src]) into one 8B scattered store
__global__ void place_kernel(const int* __restrict__ src, const int* __restrict__ dst,
                             const float* __restrict__ dis, int* __restrict__ cursor,
                             int2* __restrict__ csr, int nE, int nN)
{
    int e = blockIdx.x * 256 + threadIdx.x;
    if (e >= nE) return;
    int s = src[e], d = dst[e];
    if ((unsigned)s >= (unsigned)nN || (unsigned)d >= (unsigned)nN) return;
    int pos = atomicAdd(&cursor[d], 1);
    csr[pos] = make_int2(s, __float_as_int(dis[s]));
}

// ---------------- xw = act(in) @ W : 4 nodes per wave ----------------
// A-row elements are wave-uniform -> scalar s_loads; W row read once per k
// amortized over 4 nodes.
template<bool RELU_BIAS, bool WRITE_AGG>
__global__ void xw_kernel(const float* __restrict__ A, const float* __restrict__ W,
                          const float* __restrict__ bias, const float* __restrict__ dis,
                          float* __restrict__ xw_out, float* __restrict__ agg_out, int nN)
{
    const int wave = threadIdx.x >> 6;
    const int lane = threadIdx.x & 63;
    const int n0 = (blockIdx.x * 4 + wave) * 4;
    if (n0 >= nN) return;
    const int nc = min(4, nN - n0);
    const float* a0 = A + (size_t)n0 * HH;
    const float* a1 = A + (size_t)(n0 + (nc > 1 ? 1 : 0)) * HH;
    const float* a2 = A + (size_t)(n0 + (nc > 2 ? 2 : 0)) * HH;
    const float* a3 = A + (size_t)(n0 + (nc > 3 ? 3 : 0)) * HH;
    float acc0 = 0.f, acc1 = 0.f, acc2 = 0.f, acc3 = 0.f;
    #pragma unroll
    for (int k = 0; k < HH; k++) {
        const float w = W[k * HH + lane];
        float v0 = a0[k], v1 = a1[k], v2 = a2[k], v3 = a3[k];
        if (RELU_BIAS) {
            const float b = bias[k];
            v0 = fmaxf(v0 + b, 0.0f); v1 = fmaxf(v1 + b, 0.0f);
            v2 = fmaxf(v2 + b, 0.0f); v3 = fmaxf(v3 + b, 0.0f);
        }
        acc0 = fmaf(v0, w, acc0); acc1 = fmaf(v1, w, acc1);
        acc2 = fmaf(v2, w, acc2); acc3 = fmaf(v3, w, acc3);
    }
    float accs[4] = {acc0, acc1, acc2, acc3};
    #pragma unroll
    for (int j = 0; j < 4; j++) {
        if (j < nc) {
            const int n = n0 + j;
            xw_out[(size_t)n * HH + lane] = accs[j];
            if (WRITE_AGG) {
                const float d = dis[n];
                agg_out[(size_t)n * HH + lane] = accs[j] * d * d;
            }
        }
    }
}

// ---------------- gather: wave per node, 8-deep load pipeline ----------------
template<bool FINAL>
__global__ void gather_kernel(const float* __restrict__ xw, const float* __restrict__ dis,
                              const int* __restrict__ row_ptr, const int* __restrict__ deg,
                              const int2* __restrict__ csr,
                              float* __restrict__ agg_out,
                              const float* __restrict__ b2, const float* __restrict__ W_lin,
                              const float* __restrict__ b_lin, float* __restrict__ out, int nN)
{
    const int wave = threadIdx.x >> 6;
    const int lane = threadIdx.x & 63;
    const int n = blockIdx.x * 4 + wave;
    if (n >= nN) return;
    const float dn = dis[n];
    float v = xw[(size_t)n * HH + lane] * dn;   // self-loop
    const int start = row_ptr[n];
    const int end   = start + deg[n];
    int i = start;
    for (; i + 8 <= end; i += 8) {
        int2 c[8];
        #pragma unroll
        for (int u = 0; u < 8; u++) c[u] = csr[i + u];
        float xv[8];
        #pragma unroll
        for (int u = 0; u < 8; u++) xv[u] = xw[(size_t)c[u].x * HH + lane];
        #pragma unroll
        for (int u = 0; u < 8; u++) v = fmaf(xv[u], __int_as_float(c[u].y), v);
    }
    for (; i < end; i++) {
        int2 c = csr[i];
        v = fmaf(xw[(size_t)c.x * HH + lane], __int_as_float(c.y), v);
    }
    v *= dn;
    if (FINAL) {
        float val = fmaxf(v + b2[lane], 0.0f) * W_lin[lane];
        #pragma unroll
        for (int off = 32; off > 0; off >>= 1) val += __shfl_down(val, off);
        if (lane == 0) out[n] = val + b_lin[0];
    } else {
        agg_out[(size_t)n * HH + lane] = v;
    }
}

// ---------------- fallback: atomic scatter path ----------------
__global__ void scatter_kernel(const float* __restrict__ xw, const float* __restrict__ dis,
                               const int* __restrict__ src, const int* __restrict__ dst,
                               float* __restrict__ agg, int nE, int nN)
{
    const int e = blockIdx.x * 4 + (threadIdx.x >> 6);
    const int lane = threadIdx.x & 63;
    if (e >= nE) return;
    int s = src[e], d = dst[e];
    if ((unsigned)s >= (unsigned)nN || (unsigned)d >= (unsigned)nN) return;
    const float coef = dis[s] * dis[d];
    const float v = xw[(size_t)s * HH + lane] * coef;
    atomicAdd(&agg[(size_t)d * HH + lane], v);
}

__global__ void head_kernel(const float* __restrict__ agg, const float* __restrict__ b2,
                            const float* __restrict__ W_lin, const float* __restrict__ b_lin,
                            float* __restrict__ out, int nN)
{
    const int wave = threadIdx.x >> 6;
    const int lane = threadIdx.x & 63;
    const int n = blockIdx.x * 4 + wave;
    if (n >= nN) return;
    float v = fmaxf(agg[(size_t)n * HH + lane] + b2[lane], 0.0f) * W_lin[lane];
    #pragma unroll
    for (int off = 32; off > 0; off >>= 1) v += __shfl_down(v, off);
    if (lane == 0) out[n] = v + b_lin[0];
}

extern "C" void kernel_launch(void* const* d_in, const int* in_sizes, int n_in,
                              void* d_out, int out_size, void* d_ws, size_t ws_size,
                              hipStream_t stream)
{
    const float* x     = (const float*)d_in[0];
    const int*   edge  = (const int*)d_in[1];
    const float* W_ih  = (const float*)d_in[2];
    const float* W_hh  = (const float*)d_in[3];
    const float* b_ih  = (const float*)d_in[4];
    const float* b_hh  = (const float*)d_in[5];
    const float* W1    = (const float*)d_in[6];
    const float* b1    = (const float*)d_in[7];
    const float* W2    = (const float*)d_in[8];
    const float* b2    = (const float*)d_in[9];
    const float* W_lin = (const float*)d_in[10];
    const float* b_lin = (const float*)d_in[11];
    float* out = (float*)d_out;

    const int nN = in_sizes[0] / (WW * FF);   // 100000
    const int nE = in_sizes[1] / 2;           // 1600000
    const int* src = edge;
    const int* dst = edge + nE;

    float* ws = (float*)d_ws;
    const size_t npad = ((size_t)nN + 255) & ~(size_t)255;
    float* dis = ws;                           // [N]
    float* A   = ws + npad;                    // [N,64]
    float* B   = A + (size_t)nN * HH;          // [N,64]
    float* C   = B + (size_t)nN * HH;          // [N,64]
    int*   deg_i   = (int*)(C + (size_t)nN * HH);   // [N]
    int*   row_ptr = deg_i + npad;                  // [N]
    int*   cursor  = row_ptr + npad;                // [N]
    int2*  csr     = (int2*)(cursor + npad);        // [E] packed (src, dis-bits)

    const size_t need = (npad + 3 * (size_t)nN * HH + 3 * npad + 2 * (size_t)nE) * 4;
    const bool use_csr = (ws_size >= need);

    const int gN256 = (nN + 255) / 256;
    const int gE256 = (nE + 255) / 256;
    const int gN4   = (nN + 3) / 4;
    const int gN16  = (nN + 15) / 16;

    if (use_csr) {
        hipMemsetAsync(deg_i, 0, (size_t)nN * 4, stream);
        deg_int_kernel<<<gE256, 256, 0, stream>>>(dst, deg_i, nE, nN);
        scan_kernel<<<1, 1024, 0, stream>>>(deg_i, row_ptr, cursor, dis, nN);
        place_kernel<<<gE256, 256, 0, stream>>>(src, dst, dis, cursor, csr, nE, nN);

        lstm_mfma_kernel<<<(nN + 63) / 64, 256, 0, stream>>>(x, W_ih, W_hh, b_ih, b_hh, A, nN);

        xw_kernel<false, false><<<gN16, 256, 0, stream>>>(A, W1, nullptr, dis, B, nullptr, nN);
        gather_kernel<false><<<gN4, 256, 0, stream>>>(B, dis, row_ptr, deg_i, csr,
                                                      C, nullptr, nullptr, nullptr, nullptr, nN);
        xw_kernel<true, false><<<gN16, 256, 0, stream>>>(C, W2, b1, dis, B, nullptr, nN);
        gather_kernel<true><<<gN4, 256, 0, stream>>>(B, dis, row_ptr, deg_i, csr,
                                                     nullptr, b2, W_lin, b_lin, out, nN);
    } else {
        hipMemsetAsync(deg_i, 0, (size_t)nN * 4, stream);
        deg_int_kernel<<<gE256, 256, 0, stream>>>(dst, deg_i, nE, nN);
        dis_from_deg_kernel<<<gN256, 256, 0, stream>>>(deg_i, dis, nN);

        lstm_mfma_kernel<<<(nN + 63) / 64, 256, 0, stream>>>(x, W_ih, W_hh, b_ih, b_hh, A, nN);

        xw_kernel<false, true><<<gN16, 256, 0, stream>>>(A, W1, nullptr, dis, B, C, nN);
        scatter_kernel<<<(nE + 3) / 4, 256, 0, stream>>>(B, dis, src, dst, C, nE, nN);

        xw_kernel<true, true><<<gN16, 256, 0, stream>>>(C, W2, b1, dis, A, B, nN);
        scatter_kernel<<<(nE + 3) / 4, 256, 0, stream>>>(A, dis, src, dst, B, nE, nN);

        head_kernel<<<gN4, 256, 0, stream>>>(B, b2, W_lin, b_lin, out, nN);
    }
}

// Round 11
// 1465.321 us; speedup vs baseline: 1.5817x; 1.5817x over previous
//
#include <hip/hip_runtime.h>
#include <math.h>

#define WW 32
#define FF 16
#define HH 64

typedef __attribute__((ext_vector_type(8))) short bf16x8;
typedef __attribute__((ext_vector_type(4))) float f32x4;

__device__ __forceinline__ unsigned short bf16h(float f) {   // RNE round
    unsigned int u = __float_as_uint(f);
    unsigned int r = (u + 0x7FFFu + ((u >> 16) & 1u)) >> 16;
    return (unsigned short)r;
}
__device__ __forceinline__ float fsig(float v)  { return __fdividef(1.0f, 1.0f + __expf(-v)); }
__device__ __forceinline__ float ftanh(float v) { return 1.0f - __fdividef(2.0f, 1.0f + __expf(2.0f * v)); }

// trunc-split: hi = trunc-bf16(v), lo = trunc-bf16(v - hi)
__device__ __forceinline__ void tsplit8(const float* v, bf16x8& hi, bf16x8& lo) {
    #pragma unroll
    for (int i = 0; i < 8; i++) {
        unsigned int u = __float_as_uint(v[i]);
        hi[i] = (short)(u >> 16);
        float lf = v[i] - __uint_as_float(u & 0xFFFF0000u);
        lo[i] = (short)(__float_as_uint(lf) >> 16);
    }
}

// ---------------- LSTM via MFMA (R8 kernel, proven 838us, no spill) ----------------
__global__ __launch_bounds__(256, 2) void lstm_mfma_kernel(
    const float* __restrict__ x,      // [N,32,16]
    const float* __restrict__ W_ih,   // [256,16]
    const float* __restrict__ W_hh,   // [256,64]
    const float* __restrict__ b_ih,   // [256]
    const float* __restrict__ b_hh,   // [256]
    float* __restrict__ h_out,        // [N,64]
    int nN)
{
    __shared__ short Zs[2][2][64][64];   // 32768 B
    __shared__ short Xs[2][64][32];      // 8192 B : [node][xh(16)|xl(16)]
    const int tid  = threadIdx.x;
    const int lane = tid & 63;
    const int wv   = tid >> 6;
    const int l15  = lane & 15;
    const int g    = lane >> 4;
    const int n0   = blockIdx.x * 64;

    bf16x8 Bh[4][2], Bl[4][2], Bx[4];
    float bias[4];
    #pragma unroll
    for (int gate = 0; gate < 4; gate++) {
        const int j = 64 * gate + 16 * wv + l15;
        bias[gate] = b_ih[j] + b_hh[j];
        #pragma unroll
        for (int q = 0; q < 2; q++) {
            const float* wr = W_hh + j * HH + 32 * q + 8 * g;
            float v[8];
            float4 a = reinterpret_cast<const float4*>(wr)[0];
            float4 b = reinterpret_cast<const float4*>(wr)[1];
            v[0]=a.x; v[1]=a.y; v[2]=a.z; v[3]=a.w; v[4]=b.x; v[5]=b.y; v[6]=b.z; v[7]=b.w;
            tsplit8(v, Bh[gate][q], Bl[gate][q]);
        }
        {
            const float* wr = W_ih + j * FF + 8 * (g & 1);
            float4 a = reinterpret_cast<const float4*>(wr)[0];
            float4 b = reinterpret_cast<const float4*>(wr)[1];
            float v[8] = {a.x,a.y,a.z,a.w,b.x,b.y,b.z,b.w};
            bf16x8 bx;
            #pragma unroll
            for (int i = 0; i < 8; i++) bx[i] = (short)bf16h(v[i]);
            Bx[gate] = bx;
        }
    }

    {
        int4* zz = (int4*)(&Zs[0][0][0][0]);
        #pragma unroll
        for (int c = 0; c < 4; c++) zz[c * 256 + tid] = make_int4(0, 0, 0, 0);
        int gn = n0 + (tid >> 2); if (gn >= nN) gn = nN - 1;
        const float4 xf = *reinterpret_cast<const float4*>(x + (size_t)gn * (WW * FF) + (tid & 3) * 4);
        unsigned int u0 = __float_as_uint(xf.x), u1 = __float_as_uint(xf.y);
        unsigned int u2 = __float_as_uint(xf.z), u3 = __float_as_uint(xf.w);
        short4 hs = make_short4((short)(u0>>16), (short)(u1>>16), (short)(u2>>16), (short)(u3>>16));
        float f0 = xf.x - __uint_as_float(u0 & 0xFFFF0000u);
        float f1 = xf.y - __uint_as_float(u1 & 0xFFFF0000u);
        float f2 = xf.z - __uint_as_float(u2 & 0xFFFF0000u);
        float f3 = xf.w - __uint_as_float(u3 & 0xFFFF0000u);
        short4 ls = make_short4((short)(__float_as_uint(f0)>>16), (short)(__float_as_uint(f1)>>16),
                                (short)(__float_as_uint(f2)>>16), (short)(__float_as_uint(f3)>>16));
        *reinterpret_cast<short4*>(&Xs[0][tid >> 2][(tid & 3) * 4])      = hs;
        *reinterpret_cast<short4*>(&Xs[0][tid >> 2][16 + (tid & 3) * 4]) = ls;
    }
    __syncthreads();

    const char* zbase  = (const char*)Zs;
    char*       zwbase = (char*)Zs;
    const char* xbase  = (const char*)Xs;

    const int aoff0 = l15 * 128 + ((g ^ (l15 & 7)) * 16);
    const int aoff1 = l15 * 128 + (((4 + g) ^ (l15 & 7)) * 16);
    const int xoff  = l15 * 64 + g * 16;
    const int wblk  = 2 * wv + (l15 >> 3);
    const int wsh   = (l15 & 7) * 2;

    f32x4 cst[4] = {{0.f,0.f,0.f,0.f},{0.f,0.f,0.f,0.f},{0.f,0.f,0.f,0.f},{0.f,0.f,0.f,0.f}};

    #pragma unroll 1
    for (int t = 0; t < WW; t++) {
        const int buf = t & 1;

        int gn = n0 + (tid >> 2); if (gn >= nN) gn = nN - 1;
        const int tn = (t + 1 < WW) ? (t + 1) : t;
        const float4 xf = *reinterpret_cast<const float4*>(x + (size_t)gn * (WW * FF) + tn * FF + (tid & 3) * 4);

        #pragma unroll
        for (int rt = 0; rt < 4; rt++) {
            const bf16x8 Ah0 = *reinterpret_cast<const bf16x8*>(zbase + buf*16384 + 0*8192 + rt*2048 + aoff0);
            const bf16x8 Ah1 = *reinterpret_cast<const bf16x8*>(zbase + buf*16384 + 0*8192 + rt*2048 + aoff1);
            const bf16x8 Al0 = *reinterpret_cast<const bf16x8*>(zbase + buf*16384 + 1*8192 + rt*2048 + aoff0);
            const bf16x8 Al1 = *reinterpret_cast<const bf16x8*>(zbase + buf*16384 + 1*8192 + rt*2048 + aoff1);
            const bf16x8 Ax  = *reinterpret_cast<const bf16x8*>(xbase + buf*4096 + rt*1024 + xoff);
            f32x4 acc[4];
            #pragma unroll
            for (int gate = 0; gate < 4; gate++) {
                f32x4 ini = {bias[gate], bias[gate], bias[gate], bias[gate]};
                acc[gate] = ini;
            }
            #pragma unroll
            for (int gate = 0; gate < 4; gate++) {
                acc[gate] = __builtin_amdgcn_mfma_f32_16x16x32_bf16(Ah0, Bh[gate][0], acc[gate], 0, 0, 0);
                acc[gate] = __builtin_amdgcn_mfma_f32_16x16x32_bf16(Al0, Bh[gate][0], acc[gate], 0, 0, 0);
                acc[gate] = __builtin_amdgcn_mfma_f32_16x16x32_bf16(Ah0, Bl[gate][0], acc[gate], 0, 0, 0);
                acc[gate] = __builtin_amdgcn_mfma_f32_16x16x32_bf16(Ah1, Bh[gate][1], acc[gate], 0, 0, 0);
                acc[gate] = __builtin_amdgcn_mfma_f32_16x16x32_bf16(Al1, Bh[gate][1], acc[gate], 0, 0, 0);
                acc[gate] = __builtin_amdgcn_mfma_f32_16x16x32_bf16(Ah1, Bl[gate][1], acc[gate], 0, 0, 0);
                acc[gate] = __builtin_amdgcn_mfma_f32_16x16x32_bf16(Ax,  Bx[gate],    acc[gate], 0, 0, 0);
            }
            #pragma unroll
            for (int r = 0; r < 4; r++) {
                const float ig = fsig(acc[0][r]);
                const float fg = fsig(acc[1][r]);
                const float gg = ftanh(acc[2][r]);
                const float og = fsig(acc[3][r]);
                const float c  = fg * cst[rt][r] + ig * gg;
                cst[rt][r] = c;
                const float h  = og * ftanh(c);
                if (t < WW - 1) {
                    const int node = 16 * rt + 4 * g + r;
                    const int sw   = ((wblk ^ ((4 * g + r) & 7)) * 16) + wsh;
                    char* wp = zwbase + (buf ^ 1) * 16384 + node * 128 + sw;
                    unsigned int u = __float_as_uint(h);
                    *(short*)(wp)        = (short)(u >> 16);
                    float lf = h - __uint_as_float(u & 0xFFFF0000u);
                    *(short*)(wp + 8192) = (short)(__float_as_uint(lf) >> 16);
                } else {
                    const int node = n0 + 16 * rt + 4 * g + r;
                    if (node < nN) h_out[(size_t)node * HH + 16 * wv + l15] = h;
                }
            }
        }
        if (t < WW - 1) {
            unsigned int u0 = __float_as_uint(xf.x), u1 = __float_as_uint(xf.y);
            unsigned int u2 = __float_as_uint(xf.z), u3 = __float_as_uint(xf.w);
            short4 hs = make_short4((short)(u0>>16), (short)(u1>>16), (short)(u2>>16), (short)(u3>>16));
            float f0 = xf.x - __uint_as_float(u0 & 0xFFFF0000u);
            float f1 = xf.y - __uint_as_float(u1 & 0xFFFF0000u);
            float f2 = xf.z - __uint_as_float(u2 & 0xFFFF0000u);
            float f3 = xf.w - __uint_as_float(u3 & 0xFFFF0000u);
            short4 ls = make_short4((short)(__float_as_uint(f0)>>16), (short)(__float_as_uint(f1)>>16),
                                    (short)(__float_as_uint(f2)>>16), (short)(__float_as_uint(f3)>>16));
            *reinterpret_cast<short4*>(&Xs[buf ^ 1][tid >> 2][(tid & 3) * 4])      = hs;
            *reinterpret_cast<short4*>(&Xs[buf ^ 1][tid >> 2][16 + (tid & 3) * 4]) = ls;
        }
        __syncthreads();
    }
}

// ---------------- CSR build ----------------
__global__ void zero_int_kernel(int* __restrict__ p, int n) {
    int i = blockIdx.x * 256 + threadIdx.x;
    if (i < n) p[i] = 0;
}

__global__ void deg_int_kernel(const int* __restrict__ dst, int* __restrict__ deg, int nE, int nN) {
    int e = blockIdx.x * 256 + threadIdx.x;
    if (e < nE) {
        int d = dst[e];
        if ((unsigned)d < (unsigned)nN) atomicAdd(&deg[d], 1);
    }
}

__global__ void dis_from_deg_kernel(const int* __restrict__ deg, float* __restrict__ dis, int nN) {
    int i = blockIdx.x * 256 + threadIdx.x;
    if (i < nN) dis[i] = rsqrtf((float)deg[i] + 1.0f);
}

__global__ __launch_bounds__(1024) void scan_kernel(const int* __restrict__ deg,
                                                    int* __restrict__ row_ptr,
                                                    int* __restrict__ cursor, int nN)
{
    __shared__ int part[1024];
    const int tid = threadIdx.x;
    const int chunk = (nN + 1023) / 1024;
    const int s = tid * chunk;
    const int e = min(s + chunk, nN);
    int sum = 0;
    for (int i = s; i < e; i++) sum += deg[i];
    part[tid] = sum;
    __syncthreads();
    if (tid == 0) {
        int acc = 0;
        for (int i = 0; i < 1024; i++) { int v = part[i]; part[i] = acc; acc += v; }
    }
    __syncthreads();
    int acc = part[tid];
    for (int i = s; i < e; i++) {
        row_ptr[i] = acc;
        cursor[i]  = acc;
        acc += deg[i];
    }
}

__global__ void place_kernel(const int* __restrict__ src, const int* __restrict__ dst,
                             const float* __restrict__ dis, int* __restrict__ cursor,
                             int* __restrict__ csr_src, float* __restrict__ csr_dis,
                             int nE, int nN)
{
    int e = blockIdx.x * 256 + threadIdx.x;
    if (e >= nE) return;
    int s = src[e], d = dst[e];
    if ((unsigned)s >= (unsigned)nN || (unsigned)d >= (unsigned)nN) return;
    int pos = atomicAdd(&cursor[d], 1);
    csr_src[pos] = s;
    csr_dis[pos] = dis[s];
}

// ---------------- xw = act(in) @ W ----------------
template<bool RELU_BIAS, bool WRITE_AGG>
__global__ void xw_kernel(const float* __restrict__ A, const float* __restrict__ W,
                          const float* __restrict__ bias, const float* __restrict__ dis,
                          float* __restrict__ xw_out, float* __restrict__ agg_out, int nN)
{
    const int wave = threadIdx.x >> 6;
    const int lane = threadIdx.x & 63;
    const int n = blockIdx.x * 4 + wave;
    if (n >= nN) return;
    const float* arow = A + (size_t)n * HH;
    float acc = 0.0f;
    #pragma unroll
    for (int k = 0; k < HH; k++) {
        float a = arow[k];
        if (RELU_BIAS) a = fmaxf(a + bias[k], 0.0f);
        acc = fmaf(a, W[k * HH + lane], acc);
    }
    xw_out[(size_t)n * HH + lane] = acc;
    if (WRITE_AGG) {
        const float d = dis[n];
        agg_out[(size_t)n * HH + lane] = acc * d * d;
    }
}

// ---------------- gather: wave per node, 8-deep load pipeline ----------------
// SINGLE CHANGE vs the 1518us config: edge-loop unroll 2 -> 8 (8 independent
// xw-row loads in flight to cover L2/L3 latency).
template<bool FINAL>
__global__ void gather_kernel(const float* __restrict__ xw, const float* __restrict__ dis,
                              const int* __restrict__ row_ptr, const int* __restrict__ deg,
                              const int* __restrict__ csr_src, const float* __restrict__ csr_dis,
                              float* __restrict__ agg_out,
                              const float* __restrict__ b2, const float* __restrict__ W_lin,
                              const float* __restrict__ b_lin, float* __restrict__ out, int nN)
{
    const int wave = threadIdx.x >> 6;
    const int lane = threadIdx.x & 63;
    const int n = blockIdx.x * 4 + wave;
    if (n >= nN) return;
    const float dn = dis[n];
    float v = xw[(size_t)n * HH + lane] * dn;   // self-loop
    const int start = row_ptr[n];
    const int end   = start + deg[n];
    int i = start;
    for (; i + 8 <= end; i += 8) {
        int   s[8];
        float c[8];
        #pragma unroll
        for (int u = 0; u < 8; u++) { s[u] = csr_src[i + u]; c[u] = csr_dis[i + u]; }
        float xv[8];
        #pragma unroll
        for (int u = 0; u < 8; u++) xv[u] = xw[(size_t)s[u] * HH + lane];
        #pragma unroll
        for (int u = 0; u < 8; u++) v = fmaf(xv[u], c[u], v);
    }
    for (; i < end; i++) {
        v = fmaf(xw[(size_t)csr_src[i] * HH + lane], csr_dis[i], v);
    }
    v *= dn;
    if (FINAL) {
        float val = fmaxf(v + b2[lane], 0.0f) * W_lin[lane];
        #pragma unroll
        for (int off = 32; off > 0; off >>= 1) val += __shfl_down(val, off);
        if (lane == 0) out[n] = val + b_lin[0];
    } else {
        agg_out[(size_t)n * HH + lane] = v;
    }
}

// ---------------- fallback: atomic scatter path ----------------
__global__ void scatter_kernel(const float* __restrict__ xw, const float* __restrict__ dis,
                               const int* __restrict__ src, const int* __restrict__ dst,
                               float* __restrict__ agg, int nE, int nN)
{
    const int e = blockIdx.x * 4 + (threadIdx.x >> 6);
    const int lane = threadIdx.x & 63;
    if (e >= nE) return;
    int s = src[e], d = dst[e];
    if ((unsigned)s >= (unsigned)nN || (unsigned)d >= (unsigned)nN) return;
    const float coef = dis[s] * dis[d];
    const float v = xw[(size_t)s * HH + lane] * coef;
    atomicAdd(&agg[(size_t)d * HH + lane], v);
}

__global__ void head_kernel(const float* __restrict__ agg, const float* __restrict__ b2,
                            const float* __restrict__ W_lin, const float* __restrict__ b_lin,
                            float* __restrict__ out, int nN)
{
    const int wave = threadIdx.x >> 6;
    const int lane = threadIdx.x & 63;
    const int n = blockIdx.x * 4 + wave;
    if (n >= nN) return;
    float v = fmaxf(agg[(size_t)n * HH + lane] + b2[lane], 0.0f) * W_lin[lane];
    #pragma unroll
    for (int off = 32; off > 0; off >>= 1) v += __shfl_down(v, off);
    if (lane == 0) out[n] = v + b_lin[0];
}

extern "C" void kernel_launch(void* const* d_in, const int* in_sizes, int n_in,
                              void* d_out, int out_size, void* d_ws, size_t ws_size,
                              hipStream_t stream)
{
    const float* x     = (const float*)d_in[0];
    const int*   edge  = (const int*)d_in[1];
    const float* W_ih  = (const float*)d_in[2];
    const float* W_hh  = (const float*)d_in[3];
    const float* b_ih  = (const float*)d_in[4];
    const float* b_hh  = (const float*)d_in[5];
    const float* W1    = (const float*)d_in[6];
    const float* b1    = (const float*)d_in[7];
    const float* W2    = (const float*)d_in[8];
    const float* b2    = (const float*)d_in[9];
    const float* W_lin = (const float*)d_in[10];
    const float* b_lin = (const float*)d_in[11];
    float* out = (float*)d_out;

    const int nN = in_sizes[0] / (WW * FF);   // 100000
    const int nE = in_sizes[1] / 2;           // 1600000
    const int* src = edge;
    const int* dst = edge + nE;

    float* ws = (float*)d_ws;
    const size_t npad = ((size_t)nN + 255) & ~(size_t)255;
    float* dis = ws;                           // [N]
    float* A   = ws + npad;                    // [N,64]
    float* B   = A + (size_t)nN * HH;          // [N,64]
    float* C   = B + (size_t)nN * HH;          // [N,64]
    int*   deg_i   = (int*)(C + (size_t)nN * HH);   // [N]
    int*   row_ptr = deg_i + npad;                  // [N]
    int*   cursor  = row_ptr + npad;                // [N]
    int*   csr_src = cursor + npad;                 // [E]
    float* csr_dis = (float*)(csr_src + nE);        // [E]

    const size_t need = (npad + 3 * (size_t)nN * HH + 3 * npad + 2 * (size_t)nE) * 4;
    const bool use_csr = (ws_size >= need);

    const int gN256 = (nN + 255) / 256;
    const int gE256 = (nE + 255) / 256;
    const int gN4   = (nN + 3) / 4;

    if (use_csr) {
        zero_int_kernel<<<gN256, 256, 0, stream>>>(deg_i, nN);
        deg_int_kernel<<<gE256, 256, 0, stream>>>(dst, deg_i, nE, nN);
        dis_from_deg_kernel<<<gN256, 256, 0, stream>>>(deg_i, dis, nN);
        scan_kernel<<<1, 1024, 0, stream>>>(deg_i, row_ptr, cursor, nN);
        place_kernel<<<gE256, 256, 0, stream>>>(src, dst, dis, cursor, csr_src, csr_dis, nE, nN);

        lstm_mfma_kernel<<<(nN + 63) / 64, 256, 0, stream>>>(x, W_ih, W_hh, b_ih, b_hh, A, nN);

        xw_kernel<false, false><<<gN4, 256, 0, stream>>>(A, W1, nullptr, dis, B, nullptr, nN);
        gather_kernel<false><<<gN4, 256, 0, stream>>>(B, dis, row_ptr, deg_i, csr_src, csr_dis,
                                                      C, nullptr, nullptr, nullptr, nullptr, nN);
        xw_kernel<true, false><<<gN4, 256, 0, stream>>>(C, W2, b1, dis, B, nullptr, nN);
        gather_kernel<true><<<gN4, 256, 0, stream>>>(B, dis, row_ptr, deg_i, csr_src, csr_dis,
                                                     nullptr, b2, W_lin, b_lin, out, nN);
    } else {
        zero_int_kernel<<<gN256, 256, 0, stream>>>(deg_i, nN);
        deg_int_kernel<<<gE256, 256, 0, stream>>>(dst, deg_i, nE, nN);
        dis_from_deg_kernel<<<gN256, 256, 0, stream>>>(deg_i, dis, nN);

        lstm_mfma_kernel<<<(nN + 63) / 64, 256, 0, stream>>>(x, W_ih, W_hh, b_ih, b_hh, A, nN);

        xw_kernel<false, true><<<gN4, 256, 0, stream>>>(A, W1, nullptr, dis, B, C, nN);
        scatter_kernel<<<(nE + 3) / 4, 256, 0, stream>>>(B, dis, src, dst, C, nE, nN);

        xw_kernel<true, true><<<gN4, 256, 0, stream>>>(C, W2, b1, dis, A, B, nN);
        scatter_kernel<<<(nE + 3) / 4, 256, 0, stream>>>(A, dis, src, dst, B, nE, nN);

        head_kernel<<<gN4, 256, 0, stream>>>(B, b2, W_lin, b_lin, out, nN);
    }
}

// Round 12
// 1182.039 us; speedup vs baseline: 1.9608x; 1.2397x over previous
//
#include <hip/hip_runtime.h>
#include <math.h>

#define WW 32
#define FF 16
#define HH 64

typedef __attribute__((ext_vector_type(8))) short bf16x8;
typedef __attribute__((ext_vector_type(4))) float f32x4;

__device__ __forceinline__ unsigned short bf16h(float f) {   // RNE round
    unsigned int u = __float_as_uint(f);
    unsigned int r = (u + 0x7FFFu + ((u >> 16) & 1u)) >> 16;
    return (unsigned short)r;
}

__device__ __forceinline__ float fexp2(float x) {
#if __has_builtin(__builtin_amdgcn_exp2f)
    return __builtin_amdgcn_exp2f(x);
#else
    return exp2f(x);
#endif
}
__device__ __forceinline__ float frcp(float x) {
#if __has_builtin(__builtin_amdgcn_rcpf)
    return __builtin_amdgcn_rcpf(x);
#else
    return 1.0f / x;
#endif
}
// minimal-VALU activations: fsig = rcp(1+2^(-x*log2e)) [4 instr],
// ftanh = 1 - 2*rcp(1+2^(x*2log2e)) [5 instr]
__device__ __forceinline__ float fsig(float v)  { return frcp(1.0f + fexp2(v * -1.44269504f)); }
__device__ __forceinline__ float ftanh(float v) { return fmaf(-2.0f, frcp(1.0f + fexp2(v * 2.88539008f)), 1.0f); }

// trunc-split: hi = trunc-bf16(v), lo = trunc-bf16(v - hi)
__device__ __forceinline__ void tsplit8(const float* v, bf16x8& hi, bf16x8& lo) {
    #pragma unroll
    for (int i = 0; i < 8; i++) {
        unsigned int u = __float_as_uint(v[i]);
        hi[i] = (short)(u >> 16);
        float lf = v[i] - __uint_as_float(u & 0xFFFF0000u);
        lo[i] = (short)(__float_as_uint(lf) >> 16);
    }
}

// ---------------- LSTM via MFMA (R8 structure; cheap-activation epilogue) ----------------
__global__ __launch_bounds__(256, 2) void lstm_mfma_kernel(
    const float* __restrict__ x,      // [N,32,16]
    const float* __restrict__ W_ih,   // [256,16]
    const float* __restrict__ W_hh,   // [256,64]
    const float* __restrict__ b_ih,   // [256]
    const float* __restrict__ b_hh,   // [256]
    float* __restrict__ h_out,        // [N,64]
    int nN)
{
    __shared__ short Zs[2][2][64][64];   // 32768 B
    __shared__ short Xs[2][64][32];      // 8192 B : [node][xh(16)|xl(16)]
    const int tid  = threadIdx.x;
    const int lane = tid & 63;
    const int wv   = tid >> 6;
    const int l15  = lane & 15;
    const int g    = lane >> 4;
    const int n0   = blockIdx.x * 64;

    bf16x8 Bh[4][2], Bl[4][2], Bx[4];
    float bias[4];
    #pragma unroll
    for (int gate = 0; gate < 4; gate++) {
        const int j = 64 * gate + 16 * wv + l15;
        bias[gate] = b_ih[j] + b_hh[j];
        #pragma unroll
        for (int q = 0; q < 2; q++) {
            const float* wr = W_hh + j * HH + 32 * q + 8 * g;
            float v[8];
            float4 a = reinterpret_cast<const float4*>(wr)[0];
            float4 b = reinterpret_cast<const float4*>(wr)[1];
            v[0]=a.x; v[1]=a.y; v[2]=a.z; v[3]=a.w; v[4]=b.x; v[5]=b.y; v[6]=b.z; v[7]=b.w;
            tsplit8(v, Bh[gate][q], Bl[gate][q]);
        }
        {
            const float* wr = W_ih + j * FF + 8 * (g & 1);
            float4 a = reinterpret_cast<const float4*>(wr)[0];
            float4 b = reinterpret_cast<const float4*>(wr)[1];
            float v[8] = {a.x,a.y,a.z,a.w,b.x,b.y,b.z,b.w};
            bf16x8 bx;
            #pragma unroll
            for (int i = 0; i < 8; i++) bx[i] = (short)bf16h(v[i]);
            Bx[gate] = bx;
        }
    }

    {
        int4* zz = (int4*)(&Zs[0][0][0][0]);
        #pragma unroll
        for (int c = 0; c < 4; c++) zz[c * 256 + tid] = make_int4(0, 0, 0, 0);
        int gn = n0 + (tid >> 2); if (gn >= nN) gn = nN - 1;
        const float4 xf = *reinterpret_cast<const float4*>(x + (size_t)gn * (WW * FF) + (tid & 3) * 4);
        unsigned int u0 = __float_as_uint(xf.x), u1 = __float_as_uint(xf.y);
        unsigned int u2 = __float_as_uint(xf.z), u3 = __float_as_uint(xf.w);
        short4 hs = make_short4((short)(u0>>16), (short)(u1>>16), (short)(u2>>16), (short)(u3>>16));
        float f0 = xf.x - __uint_as_float(u0 & 0xFFFF0000u);
        float f1 = xf.y - __uint_as_float(u1 & 0xFFFF0000u);
        float f2 = xf.z - __uint_as_float(u2 & 0xFFFF0000u);
        float f3 = xf.w - __uint_as_float(u3 & 0xFFFF0000u);
        short4 ls = make_short4((short)(__float_as_uint(f0)>>16), (short)(__float_as_uint(f1)>>16),
                                (short)(__float_as_uint(f2)>>16), (short)(__float_as_uint(f3)>>16));
        *reinterpret_cast<short4*>(&Xs[0][tid >> 2][(tid & 3) * 4])      = hs;
        *reinterpret_cast<short4*>(&Xs[0][tid >> 2][16 + (tid & 3) * 4]) = ls;
    }
    __syncthreads();

    const char* zbase  = (const char*)Zs;
    char*       zwbase = (char*)Zs;
    const char* xbase  = (const char*)Xs;

    const int aoff0 = l15 * 128 + ((g ^ (l15 & 7)) * 16);
    const int aoff1 = l15 * 128 + (((4 + g) ^ (l15 & 7)) * 16);
    const int xoff  = l15 * 64 + g * 16;
    const int wblk  = 2 * wv + (l15 >> 3);
    const int wsh   = (l15 & 7) * 2;

    f32x4 cst[4] = {{0.f,0.f,0.f,0.f},{0.f,0.f,0.f,0.f},{0.f,0.f,0.f,0.f},{0.f,0.f,0.f,0.f}};

    #pragma unroll 1
    for (int t = 0; t < WW; t++) {
        const int buf = t & 1;

        int gn = n0 + (tid >> 2); if (gn >= nN) gn = nN - 1;
        const int tn = (t + 1 < WW) ? (t + 1) : t;
        const float4 xf = *reinterpret_cast<const float4*>(x + (size_t)gn * (WW * FF) + tn * FF + (tid & 3) * 4);

        #pragma unroll
        for (int rt = 0; rt < 4; rt++) {
            const bf16x8 Ah0 = *reinterpret_cast<const bf16x8*>(zbase + buf*16384 + 0*8192 + rt*2048 + aoff0);
            const bf16x8 Ah1 = *reinterpret_cast<const bf16x8*>(zbase + buf*16384 + 0*8192 + rt*2048 + aoff1);
            const bf16x8 Al0 = *reinterpret_cast<const bf16x8*>(zbase + buf*16384 + 1*8192 + rt*2048 + aoff0);
            const bf16x8 Al1 = *reinterpret_cast<const bf16x8*>(zbase + buf*16384 + 1*8192 + rt*2048 + aoff1);
            const bf16x8 Ax  = *reinterpret_cast<const bf16x8*>(xbase + buf*4096 + rt*1024 + xoff);
            f32x4 acc[4];
            #pragma unroll
            for (int gate = 0; gate < 4; gate++) {
                f32x4 ini = {bias[gate], bias[gate], bias[gate], bias[gate]};
                acc[gate] = ini;
            }
            #pragma unroll
            for (int gate = 0; gate < 4; gate++) {
                acc[gate] = __builtin_amdgcn_mfma_f32_16x16x32_bf16(Ah0, Bh[gate][0], acc[gate], 0, 0, 0);
                acc[gate] = __builtin_amdgcn_mfma_f32_16x16x32_bf16(Al0, Bh[gate][0], acc[gate], 0, 0, 0);
                acc[gate] = __builtin_amdgcn_mfma_f32_16x16x32_bf16(Ah0, Bl[gate][0], acc[gate], 0, 0, 0);
                acc[gate] = __builtin_amdgcn_mfma_f32_16x16x32_bf16(Ah1, Bh[gate][1], acc[gate], 0, 0, 0);
                acc[gate] = __builtin_amdgcn_mfma_f32_16x16x32_bf16(Al1, Bh[gate][1], acc[gate], 0, 0, 0);
                acc[gate] = __builtin_amdgcn_mfma_f32_16x16x32_bf16(Ah1, Bl[gate][1], acc[gate], 0, 0, 0);
                acc[gate] = __builtin_amdgcn_mfma_f32_16x16x32_bf16(Ax,  Bx[gate],    acc[gate], 0, 0, 0);
            }
            #pragma unroll
            for (int r = 0; r < 4; r++) {
                const float ig = fsig(acc[0][r]);
                const float fg = fsig(acc[1][r]);
                const float gg = ftanh(acc[2][r]);
                const float og = fsig(acc[3][r]);
                const float c  = fg * cst[rt][r] + ig * gg;
                cst[rt][r] = c;
                const float h  = og * ftanh(c);
                if (t < WW - 1) {
                    const int node = 16 * rt + 4 * g + r;
                    const int sw   = ((wblk ^ ((4 * g + r) & 7)) * 16) + wsh;
                    char* wp = zwbase + (buf ^ 1) * 16384 + node * 128 + sw;
                    unsigned int u = __float_as_uint(h);
                    *(short*)(wp)        = (short)(u >> 16);
                    float lf = h - __uint_as_float(u & 0xFFFF0000u);
                    *(short*)(wp + 8192) = (short)(__float_as_uint(lf) >> 16);
                } else {
                    const int node = n0 + 16 * rt + 4 * g + r;
                    if (node < nN) h_out[(size_t)node * HH + 16 * wv + l15] = h;
                }
            }
        }
        if (t < WW - 1) {
            unsigned int u0 = __float_as_uint(xf.x), u1 = __float_as_uint(xf.y);
            unsigned int u2 = __float_as_uint(xf.z), u3 = __float_as_uint(xf.w);
            short4 hs = make_short4((short)(u0>>16), (short)(u1>>16), (short)(u2>>16), (short)(u3>>16));
            float f0 = xf.x - __uint_as_float(u0 & 0xFFFF0000u);
            float f1 = xf.y - __uint_as_float(u1 & 0xFFFF0000u);
            float f2 = xf.z - __uint_as_float(u2 & 0xFFFF0000u);
            float f3 = xf.w - __uint_as_float(u3 & 0xFFFF0000u);
            short4 ls = make_short4((short)(__float_as_uint(f0)>>16), (short)(__float_as_uint(f1)>>16),
                                    (short)(__float_as_uint(f2)>>16), (short)(__float_as_uint(f3)>>16));
            *reinterpret_cast<short4*>(&Xs[buf ^ 1][tid >> 2][(tid & 3) * 4])      = hs;
            *reinterpret_cast<short4*>(&Xs[buf ^ 1][tid >> 2][16 + (tid & 3) * 4]) = ls;
        }
        __syncthreads();
    }
}

// ---------------- CSR build ----------------
__global__ void zero_int_kernel(int* __restrict__ p, int n) {
    int i = blockIdx.x * 256 + threadIdx.x;
    if (i < n) p[i] = 0;
}

__global__ void deg_int_kernel(const int* __restrict__ dst, int* __restrict__ deg, int nE, int nN) {
    int e = blockIdx.x * 256 + threadIdx.x;
    if (e < nE) {
        int d = dst[e];
        if ((unsigned)d < (unsigned)nN) atomicAdd(&deg[d], 1);
    }
}

__global__ void dis_from_deg_kernel(const int* __restrict__ deg, float* __restrict__ dis, int nN) {
    int i = blockIdx.x * 256 + threadIdx.x;
    if (i < nN) dis[i] = rsqrtf((float)deg[i] + 1.0f);
}

// single-block scan with PARALLEL cross-thread prefix (was: serial tid0 loop
// over 1024 parts ~51us; now shfl-tree wave prefix + cross-wave stage ~2us)
__global__ __launch_bounds__(1024) void scan_kernel(const int* __restrict__ deg,
                                                    int* __restrict__ row_ptr,
                                                    int* __restrict__ cursor, int nN)
{
    __shared__ int wsum[16];
    const int tid  = threadIdx.x;
    const int lane = tid & 63;
    const int wv   = tid >> 6;
    const int chunk = (nN + 1023) / 1024;
    const int s = tid * chunk;
    const int e = min(s + chunk, nN);
    int sum = 0;
    for (int i = s; i < e; i++) sum += deg[i];

    // inclusive prefix within wave
    int inc = sum;
    #pragma unroll
    for (int off = 1; off < 64; off <<= 1) {
        int n = __shfl_up(inc, off);
        if (lane >= off) inc += n;
    }
    if (lane == 63) wsum[wv] = inc;
    __syncthreads();
    if (wv == 0) {
        int w = (lane < 16) ? wsum[lane] : 0;
        int winc = w;
        #pragma unroll
        for (int off = 1; off < 16; off <<= 1) {
            int n = __shfl_up(winc, off);
            if (lane >= off) winc += n;
        }
        if (lane < 16) wsum[lane] = winc - w;   // exclusive wave offsets
    }
    __syncthreads();
    int acc = inc - sum + wsum[wv];   // exclusive prefix for this thread's chunk
    for (int i = s; i < e; i++) {
        const int d = deg[i];
        row_ptr[i] = acc;
        cursor[i]  = acc;
        acc += d;
    }
}

__global__ void place_kernel(const int* __restrict__ src, const int* __restrict__ dst,
                             const float* __restrict__ dis, int* __restrict__ cursor,
                             int* __restrict__ csr_src, float* __restrict__ csr_dis,
                             int nE, int nN)
{
    int e = blockIdx.x * 256 + threadIdx.x;
    if (e >= nE) return;
    int s = src[e], d = dst[e];
    if ((unsigned)s >= (unsigned)nN || (unsigned)d >= (unsigned)nN) return;
    int pos = atomicAdd(&cursor[d], 1);
    csr_src[pos] = s;
    csr_dis[pos] = dis[s];
}

// ---------------- xw = act(in) @ W ----------------
template<bool RELU_BIAS, bool WRITE_AGG>
__global__ void xw_kernel(const float* __restrict__ A, const float* __restrict__ W,
                          const float* __restrict__ bias, const float* __restrict__ dis,
                          float* __restrict__ xw_out, float* __restrict__ agg_out, int nN)
{
    const int wave = threadIdx.x >> 6;
    const int lane = threadIdx.x & 63;
    const int n = blockIdx.x * 4 + wave;
    if (n >= nN) return;
    const float* arow = A + (size_t)n * HH;
    float acc = 0.0f;
    #pragma unroll
    for (int k = 0; k < HH; k++) {
        float a = arow[k];
        if (RELU_BIAS) a = fmaxf(a + bias[k], 0.0f);
        acc = fmaf(a, W[k * HH + lane], acc);
    }
    xw_out[(size_t)n * HH + lane] = acc;
    if (WRITE_AGG) {
        const float d = dis[n];
        agg_out[(size_t)n * HH + lane] = acc * d * d;
    }
}

// ---------------- gather: wave per node, 8-deep load pipeline ----------------
template<bool FINAL>
__global__ void gather_kernel(const float* __restrict__ xw, const float* __restrict__ dis,
                              const int* __restrict__ row_ptr, const int* __restrict__ deg,
                              const int* __restrict__ csr_src, const float* __restrict__ csr_dis,
                              float* __restrict__ agg_out,
                              const float* __restrict__ b2, const float* __restrict__ W_lin,
                              const float* __restrict__ b_lin, float* __restrict__ out, int nN)
{
    const int wave = threadIdx.x >> 6;
    const int lane = threadIdx.x & 63;
    const int n = blockIdx.x * 4 + wave;
    if (n >= nN) return;
    const float dn = dis[n];
    float v = xw[(size_t)n * HH + lane] * dn;   // self-loop
    const int start = row_ptr[n];
    const int end   = start + deg[n];
    int i = start;
    for (; i + 8 <= end; i += 8) {
        int   s[8];
        float c[8];
        #pragma unroll
        for (int u = 0; u < 8; u++) { s[u] = csr_src[i + u]; c[u] = csr_dis[i + u]; }
        float xv[8];
        #pragma unroll
        for (int u = 0; u < 8; u++) xv[u] = xw[(size_t)s[u] * HH + lane];
        #pragma unroll
        for (int u = 0; u < 8; u++) v = fmaf(xv[u], c[u], v);
    }
    for (; i < end; i++) {
        v = fmaf(xw[(size_t)csr_src[i] * HH + lane], csr_dis[i], v);
    }
    v *= dn;
    if (FINAL) {
        float val = fmaxf(v + b2[lane], 0.0f) * W_lin[lane];
        #pragma unroll
        for (int off = 32; off > 0; off >>= 1) val += __shfl_down(val, off);
        if (lane == 0) out[n] = val + b_lin[0];
    } else {
        agg_out[(size_t)n * HH + lane] = v;
    }
}

// ---------------- fallback: atomic scatter path ----------------
__global__ void scatter_kernel(const float* __restrict__ xw, const float* __restrict__ dis,
                               const int* __restrict__ src, const int* __restrict__ dst,
                               float* __restrict__ agg, int nE, int nN)
{
    const int e = blockIdx.x * 4 + (threadIdx.x >> 6);
    const int lane = threadIdx.x & 63;
    if (e >= nE) return;
    int s = src[e], d = dst[e];
    if ((unsigned)s >= (unsigned)nN || (unsigned)d >= (unsigned)nN) return;
    const float coef = dis[s] * dis[d];
    const float v = xw[(size_t)s * HH + lane] * coef;
    atomicAdd(&agg[(size_t)d * HH + lane], v);
}

__global__ void head_kernel(const float* __restrict__ agg, const float* __restrict__ b2,
                            const float* __restrict__ W_lin, const float* __restrict__ b_lin,
                            float* __restrict__ out, int nN)
{
    const int wave = threadIdx.x >> 6;
    const int lane = threadIdx.x & 63;
    const int n = blockIdx.x * 4 + wave;
    if (n >= nN) return;
    float v = fmaxf(agg[(size_t)n * HH + lane] + b2[lane], 0.0f) * W_lin[lane];
    #pragma unroll
    for (int off = 32; off > 0; off >>= 1) v += __shfl_down(v, off);
    if (lane == 0) out[n] = v + b_lin[0];
}

extern "C" void kernel_launch(void* const* d_in, const int* in_sizes, int n_in,
                              void* d_out, int out_size, void* d_ws, size_t ws_size,
                              hipStream_t stream)
{
    const float* x     = (const float*)d_in[0];
    const int*   edge  = (const int*)d_in[1];
    const float* W_ih  = (const float*)d_in[2];
    const float* W_hh  = (const float*)d_in[3];
    const float* b_ih  = (const float*)d_in[4];
    const float* b_hh  = (const float*)d_in[5];
    const float* W1    = (const float*)d_in[6];
    const float* b1    = (const float*)d_in[7];
    const float* W2    = (const float*)d_in[8];
    const float* b2    = (const float*)d_in[9];
    const float* W_lin = (const float*)d_in[10];
    const float* b_lin = (const float*)d_in[11];
    float* out = (float*)d_out;

    const int nN = in_sizes[0] / (WW * FF);   // 100000
    const int nE = in_sizes[1] / 2;           // 1600000
    const int* src = edge;
    const int* dst = edge + nE;

    float* ws = (float*)d_ws;
    const size_t npad = ((size_t)nN + 255) & ~(size_t)255;
    float* dis = ws;                           // [N]
    float* A   = ws + npad;                    // [N,64]
    float* B   = A + (size_t)nN * HH;          // [N,64]
    float* C   = B + (size_t)nN * HH;          // [N,64]
    int*   deg_i   = (int*)(C + (size_t)nN * HH);   // [N]
    int*   row_ptr = deg_i + npad;                  // [N]
    int*   cursor  = row_ptr + npad;                // [N]
    int*   csr_src = cursor + npad;                 // [E]
    float* csr_dis = (float*)(csr_src + nE);        // [E]

    const size_t need = (npad + 3 * (size_t)nN * HH + 3 * npad + 2 * (size_t)nE) * 4;
    const bool use_csr = (ws_size >= need);

    const int gN256 = (nN + 255) / 256;
    const int gE256 = (nE + 255) / 256;
    const int gN4   = (nN + 3) / 4;

    if (use_csr) {
        zero_int_kernel<<<gN256, 256, 0, stream>>>(deg_i, nN);
        deg_int_kernel<<<gE256, 256, 0, stream>>>(dst, deg_i, nE, nN);
        dis_from_deg_kernel<<<gN256, 256, 0, stream>>>(deg_i, dis, nN);
        scan_kernel<<<1, 1024, 0, stream>>>(deg_i, row_ptr, cursor, nN);
        place_kernel<<<gE256, 256, 0, stream>>>(src, dst, dis, cursor, csr_src, csr_dis, nE, nN);

        lstm_mfma_kernel<<<(nN + 63) / 64, 256, 0, stream>>>(x, W_ih, W_hh, b_ih, b_hh, A, nN);

        xw_kernel<false, false><<<gN4, 256, 0, stream>>>(A, W1, nullptr, dis, B, nullptr, nN);
        gather_kernel<false><<<gN4, 256, 0, stream>>>(B, dis, row_ptr, deg_i, csr_src, csr_dis,
                                                      C, nullptr, nullptr, nullptr, nullptr, nN);
        xw_kernel<true, false><<<gN4, 256, 0, stream>>>(C, W2, b1, dis, B, nullptr, nN);
        gather_kernel<true><<<gN4, 256, 0, stream>>>(B, dis, row_ptr, deg_i, csr_src, csr_dis,
                                                     nullptr, b2, W_lin, b_lin, out, nN);
    } else {
        zero_int_kernel<<<gN256, 256, 0, stream>>>(deg_i, nN);
        deg_int_kernel<<<gE256, 256, 0, stream>>>(dst, deg_i, nE, nN);
        dis_from_deg_kernel<<<gN256, 256, 0, stream>>>(deg_i, dis, nN);

        lstm_mfma_kernel<<<(nN + 63) / 64, 256, 0, stream>>>(x, W_ih, W_hh, b_ih, b_hh, A, nN);

        xw_kernel<false, true><<<gN4, 256, 0, stream>>>(A, W1, nullptr, dis, B, C, nN);
        scatter_kernel<<<(nE + 3) / 4, 256, 0, stream>>>(B, dis, src, dst, C, nE, nN);

        xw_kernel<true, true><<<gN4, 256, 0, stream>>>(C, W2, b1, dis, A, B, nN);
        scatter_kernel<<<(nE + 3) / 4, 256, 0, stream>>>(A, dis, src, dst, B, nE, nN);

        head_kernel<<<gN4, 256, 0, stream>>>(B, b2, W_lin, b_lin, out, nN);
    }
}

// Round 13
// 1110.610 us; speedup vs baseline: 2.0869x; 1.0643x over previous
//
#include <hip/hip_runtime.h>
#include <math.h>

#define WW 32
#define FF 16
#define HH 64

typedef __attribute__((ext_vector_type(8))) short bf16x8;
typedef __attribute__((ext_vector_type(4))) float f32x4;

__device__ __forceinline__ unsigned short bf16h(float f) {   // RNE round
    unsigned int u = __float_as_uint(f);
    unsigned int r = (u + 0x7FFFu + ((u >> 16) & 1u)) >> 16;
    return (unsigned short)r;
}

__device__ __forceinline__ float fexp2(float x) {
#if __has_builtin(__builtin_amdgcn_exp2f)
    return __builtin_amdgcn_exp2f(x);
#else
    return exp2f(x);
#endif
}
__device__ __forceinline__ float frcp(float x) {
#if __has_builtin(__builtin_amdgcn_rcpf)
    return __builtin_amdgcn_rcpf(x);
#else
    return 1.0f / x;
#endif
}
__device__ __forceinline__ float fsig(float v)  { return frcp(1.0f + fexp2(v * -1.44269504f)); }
__device__ __forceinline__ float ftanh(float v) { return fmaf(-2.0f, frcp(1.0f + fexp2(v * 2.88539008f)), 1.0f); }

// trunc-split: hi = trunc-bf16(v), lo = trunc-bf16(v - hi)
__device__ __forceinline__ void tsplit8(const float* v, bf16x8& hi, bf16x8& lo) {
    #pragma unroll
    for (int i = 0; i < 8; i++) {
        unsigned int u = __float_as_uint(v[i]);
        hi[i] = (short)(u >> 16);
        float lf = v[i] - __uint_as_float(u & 0xFFFF0000u);
        lo[i] = (short)(__float_as_uint(lf) >> 16);
    }
}

// ---------------- LSTM via MFMA + FUSED xw1 = h_last @ W1 ----------------
// R12 structure (514us). At t=31 h goes to Zs (not global); afterwards each
// wave computes its 16 cols of h@W1 with 6 MFMAs/rt (3-term split) and stores
// xw directly -> the standalone xw1 pass (51MB traffic + launch) is deleted.
__global__ __launch_bounds__(256, 2) void lstm_mfma_kernel(
    const float* __restrict__ x,      // [N,32,16]
    const float* __restrict__ W_ih,   // [256,16]
    const float* __restrict__ W_hh,   // [256,64]
    const float* __restrict__ b_ih,   // [256]
    const float* __restrict__ b_hh,   // [256]
    const float* __restrict__ W1,     // [64,64]  (xw = h @ W1)
    float* __restrict__ xw_out,       // [N,64]
    int nN)
{
    __shared__ short Zs[2][2][64][64];   // 32768 B
    __shared__ short Xs[2][64][32];      // 8192 B
    const int tid  = threadIdx.x;
    const int lane = tid & 63;
    const int wv   = tid >> 6;
    const int l15  = lane & 15;
    const int g    = lane >> 4;
    const int n0   = blockIdx.x * 64;

    bf16x8 Bh[4][2], Bl[4][2], Bx[4];
    float bias[4];
    #pragma unroll
    for (int gate = 0; gate < 4; gate++) {
        const int j = 64 * gate + 16 * wv + l15;
        bias[gate] = b_ih[j] + b_hh[j];
        #pragma unroll
        for (int q = 0; q < 2; q++) {
            const float* wr = W_hh + j * HH + 32 * q + 8 * g;
            float v[8];
            float4 a = reinterpret_cast<const float4*>(wr)[0];
            float4 b = reinterpret_cast<const float4*>(wr)[1];
            v[0]=a.x; v[1]=a.y; v[2]=a.z; v[3]=a.w; v[4]=b.x; v[5]=b.y; v[6]=b.z; v[7]=b.w;
            tsplit8(v, Bh[gate][q], Bl[gate][q]);
        }
        {
            const float* wr = W_ih + j * FF + 8 * (g & 1);
            float4 a = reinterpret_cast<const float4*>(wr)[0];
            float4 b = reinterpret_cast<const float4*>(wr)[1];
            float v[8] = {a.x,a.y,a.z,a.w,b.x,b.y,b.z,b.w};
            bf16x8 bx;
            #pragma unroll
            for (int i = 0; i < 8; i++) bx[i] = (short)bf16h(v[i]);
            Bx[gate] = bx;
        }
    }

    {
        int4* zz = (int4*)(&Zs[0][0][0][0]);
        #pragma unroll
        for (int c = 0; c < 4; c++) zz[c * 256 + tid] = make_int4(0, 0, 0, 0);
        int gn = n0 + (tid >> 2); if (gn >= nN) gn = nN - 1;
        const float4 xf = *reinterpret_cast<const float4*>(x + (size_t)gn * (WW * FF) + (tid & 3) * 4);
        unsigned int u0 = __float_as_uint(xf.x), u1 = __float_as_uint(xf.y);
        unsigned int u2 = __float_as_uint(xf.z), u3 = __float_as_uint(xf.w);
        short4 hs = make_short4((short)(u0>>16), (short)(u1>>16), (short)(u2>>16), (short)(u3>>16));
        float f0 = xf.x - __uint_as_float(u0 & 0xFFFF0000u);
        float f1 = xf.y - __uint_as_float(u1 & 0xFFFF0000u);
        float f2 = xf.z - __uint_as_float(u2 & 0xFFFF0000u);
        float f3 = xf.w - __uint_as_float(u3 & 0xFFFF0000u);
        short4 ls = make_short4((short)(__float_as_uint(f0)>>16), (short)(__float_as_uint(f1)>>16),
                                (short)(__float_as_uint(f2)>>16), (short)(__float_as_uint(f3)>>16));
        *reinterpret_cast<short4*>(&Xs[0][tid >> 2][(tid & 3) * 4])      = hs;
        *reinterpret_cast<short4*>(&Xs[0][tid >> 2][16 + (tid & 3) * 4]) = ls;
    }
    __syncthreads();

    const char* zbase  = (const char*)Zs;
    char*       zwbase = (char*)Zs;
    const char* xbase  = (const char*)Xs;

    const int aoff0 = l15 * 128 + ((g ^ (l15 & 7)) * 16);
    const int aoff1 = l15 * 128 + (((4 + g) ^ (l15 & 7)) * 16);
    const int xoff  = l15 * 64 + g * 16;
    const int wblk  = 2 * wv + (l15 >> 3);
    const int wsh   = (l15 & 7) * 2;

    f32x4 cst[4] = {{0.f,0.f,0.f,0.f},{0.f,0.f,0.f,0.f},{0.f,0.f,0.f,0.f},{0.f,0.f,0.f,0.f}};

    #pragma unroll 1
    for (int t = 0; t < WW; t++) {
        const int buf = t & 1;

        int gn = n0 + (tid >> 2); if (gn >= nN) gn = nN - 1;
        const int tn = (t + 1 < WW) ? (t + 1) : t;
        const float4 xf = *reinterpret_cast<const float4*>(x + (size_t)gn * (WW * FF) + tn * FF + (tid & 3) * 4);

        #pragma unroll
        for (int rt = 0; rt < 4; rt++) {
            const bf16x8 Ah0 = *reinterpret_cast<const bf16x8*>(zbase + buf*16384 + 0*8192 + rt*2048 + aoff0);
            const bf16x8 Ah1 = *reinterpret_cast<const bf16x8*>(zbase + buf*16384 + 0*8192 + rt*2048 + aoff1);
            const bf16x8 Al0 = *reinterpret_cast<const bf16x8*>(zbase + buf*16384 + 1*8192 + rt*2048 + aoff0);
            const bf16x8 Al1 = *reinterpret_cast<const bf16x8*>(zbase + buf*16384 + 1*8192 + rt*2048 + aoff1);
            const bf16x8 Ax  = *reinterpret_cast<const bf16x8*>(xbase + buf*4096 + rt*1024 + xoff);
            f32x4 acc[4];
            #pragma unroll
            for (int gate = 0; gate < 4; gate++) {
                f32x4 ini = {bias[gate], bias[gate], bias[gate], bias[gate]};
                acc[gate] = ini;
            }
            #pragma unroll
            for (int gate = 0; gate < 4; gate++) {
                acc[gate] = __builtin_amdgcn_mfma_f32_16x16x32_bf16(Ah0, Bh[gate][0], acc[gate], 0, 0, 0);
                acc[gate] = __builtin_amdgcn_mfma_f32_16x16x32_bf16(Al0, Bh[gate][0], acc[gate], 0, 0, 0);
                acc[gate] = __builtin_amdgcn_mfma_f32_16x16x32_bf16(Ah0, Bl[gate][0], acc[gate], 0, 0, 0);
                acc[gate] = __builtin_amdgcn_mfma_f32_16x16x32_bf16(Ah1, Bh[gate][1], acc[gate], 0, 0, 0);
                acc[gate] = __builtin_amdgcn_mfma_f32_16x16x32_bf16(Al1, Bh[gate][1], acc[gate], 0, 0, 0);
                acc[gate] = __builtin_amdgcn_mfma_f32_16x16x32_bf16(Ah1, Bl[gate][1], acc[gate], 0, 0, 0);
                acc[gate] = __builtin_amdgcn_mfma_f32_16x16x32_bf16(Ax,  Bx[gate],    acc[gate], 0, 0, 0);
            }
            #pragma unroll
            for (int r = 0; r < 4; r++) {
                const float ig = fsig(acc[0][r]);
                const float fg = fsig(acc[1][r]);
                const float gg = ftanh(acc[2][r]);
                const float og = fsig(acc[3][r]);
                const float c  = fg * cst[rt][r] + ig * gg;
                cst[rt][r] = c;
                const float h  = og * ftanh(c);
                // ALWAYS stage h (incl. t=31, consumed by the fused xw GEMM)
                const int node = 16 * rt + 4 * g + r;
                const int sw   = ((wblk ^ ((4 * g + r) & 7)) * 16) + wsh;
                char* wp = zwbase + (buf ^ 1) * 16384 + node * 128 + sw;
                unsigned int u = __float_as_uint(h);
                *(short*)(wp)        = (short)(u >> 16);
                float lf = h - __uint_as_float(u & 0xFFFF0000u);
                *(short*)(wp + 8192) = (short)(__float_as_uint(lf) >> 16);
            }
        }
        if (t < WW - 1) {
            unsigned int u0 = __float_as_uint(xf.x), u1 = __float_as_uint(xf.y);
            unsigned int u2 = __float_as_uint(xf.z), u3 = __float_as_uint(xf.w);
            short4 hs = make_short4((short)(u0>>16), (short)(u1>>16), (short)(u2>>16), (short)(u3>>16));
            float f0 = xf.x - __uint_as_float(u0 & 0xFFFF0000u);
            float f1 = xf.y - __uint_as_float(u1 & 0xFFFF0000u);
            float f2 = xf.z - __uint_as_float(u2 & 0xFFFF0000u);
            float f3 = xf.w - __uint_as_float(u3 & 0xFFFF0000u);
            short4 ls = make_short4((short)(__float_as_uint(f0)>>16), (short)(__float_as_uint(f1)>>16),
                                    (short)(__float_as_uint(f2)>>16), (short)(__float_as_uint(f3)>>16));
            *reinterpret_cast<short4*>(&Xs[buf ^ 1][tid >> 2][(tid & 3) * 4])      = hs;
            *reinterpret_cast<short4*>(&Xs[buf ^ 1][tid >> 2][16 + (tid & 3) * 4]) = ls;
        }
        __syncthreads();
    }

    // ---- fused xw = h_last @ W1 (h_last is in Zs buf 0: (31&1)^1 == 0) ----
    bf16x8 W1h[2], W1l[2];
    #pragma unroll
    for (int q = 0; q < 2; q++) {
        float v[8];
        #pragma unroll
        for (int i = 0; i < 8; i++)
            v[i] = W1[(32 * q + 8 * g + i) * HH + 16 * wv + l15];
        tsplit8(v, W1h[q], W1l[q]);
    }
    #pragma unroll
    for (int rt = 0; rt < 4; rt++) {
        const bf16x8 Ah0 = *reinterpret_cast<const bf16x8*>(zbase + 0*8192 + rt*2048 + aoff0);
        const bf16x8 Ah1 = *reinterpret_cast<const bf16x8*>(zbase + 0*8192 + rt*2048 + aoff1);
        const bf16x8 Al0 = *reinterpret_cast<const bf16x8*>(zbase + 1*8192 + rt*2048 + aoff0);
        const bf16x8 Al1 = *reinterpret_cast<const bf16x8*>(zbase + 1*8192 + rt*2048 + aoff1);
        f32x4 acc = {0.f, 0.f, 0.f, 0.f};
        acc = __builtin_amdgcn_mfma_f32_16x16x32_bf16(Ah0, W1h[0], acc, 0, 0, 0);
        acc = __builtin_amdgcn_mfma_f32_16x16x32_bf16(Al0, W1h[0], acc, 0, 0, 0);
        acc = __builtin_amdgcn_mfma_f32_16x16x32_bf16(Ah0, W1l[0], acc, 0, 0, 0);
        acc = __builtin_amdgcn_mfma_f32_16x16x32_bf16(Ah1, W1h[1], acc, 0, 0, 0);
        acc = __builtin_amdgcn_mfma_f32_16x16x32_bf16(Al1, W1h[1], acc, 0, 0, 0);
        acc = __builtin_amdgcn_mfma_f32_16x16x32_bf16(Ah1, W1l[1], acc, 0, 0, 0);
        #pragma unroll
        for (int r = 0; r < 4; r++) {
            const int node = n0 + 16 * rt + 4 * g + r;
            if (node < nN) xw_out[(size_t)node * HH + 16 * wv + l15] = acc[r];
        }
    }
}

// ---------------- CSR build ----------------
__global__ void zero_int_kernel(int* __restrict__ p, int n) {
    int i = blockIdx.x * 256 + threadIdx.x;
    if (i < n) p[i] = 0;
}

__global__ void deg_int_kernel(const int* __restrict__ dst, int* __restrict__ deg, int nE, int nN) {
    int e = blockIdx.x * 256 + threadIdx.x;
    if (e < nE) {
        int d = dst[e];
        if ((unsigned)d < (unsigned)nN) atomicAdd(&deg[d], 1);
    }
}

__global__ void dis_from_deg_kernel(const int* __restrict__ deg, float* __restrict__ dis, int nN) {
    int i = blockIdx.x * 256 + threadIdx.x;
    if (i < nN) dis[i] = rsqrtf((float)deg[i] + 1.0f);
}

__global__ __launch_bounds__(1024) void scan_kernel(const int* __restrict__ deg,
                                                    int* __restrict__ row_ptr,
                                                    int* __restrict__ cursor, int nN)
{
    __shared__ int wsum[16];
    const int tid  = threadIdx.x;
    const int lane = tid & 63;
    const int wv   = tid >> 6;
    const int chunk = (nN + 1023) / 1024;
    const int s = tid * chunk;
    const int e = min(s + chunk, nN);
    int sum = 0;
    for (int i = s; i < e; i++) sum += deg[i];

    int inc = sum;
    #pragma unroll
    for (int off = 1; off < 64; off <<= 1) {
        int n = __shfl_up(inc, off);
        if (lane >= off) inc += n;
    }
    if (lane == 63) wsum[wv] = inc;
    __syncthreads();
    if (wv == 0) {
        int w = (lane < 16) ? wsum[lane] : 0;
        int winc = w;
        #pragma unroll
        for (int off = 1; off < 16; off <<= 1) {
            int n = __shfl_up(winc, off);
            if (lane >= off) winc += n;
        }
        if (lane < 16) wsum[lane] = winc - w;
    }
    __syncthreads();
    int acc = inc - sum + wsum[wv];
    for (int i = s; i < e; i++) {
        const int d = deg[i];
        row_ptr[i] = acc;
        cursor[i]  = acc;
        acc += d;
    }
}

__global__ void place_kernel(const int* __restrict__ src, const int* __restrict__ dst,
                             const float* __restrict__ dis, int* __restrict__ cursor,
                             int* __restrict__ csr_src, float* __restrict__ csr_dis,
                             int nE, int nN)
{
    int e = blockIdx.x * 256 + threadIdx.x;
    if (e >= nE) return;
    int s = src[e], d = dst[e];
    if ((unsigned)s >= (unsigned)nN || (unsigned)d >= (unsigned)nN) return;
    int pos = atomicAdd(&cursor[d], 1);
    csr_src[pos] = s;
    csr_dis[pos] = dis[s];
}

// ---------------- xw = act(in) @ W ----------------
template<bool RELU_BIAS, bool WRITE_AGG>
__global__ void xw_kernel(const float* __restrict__ A, const float* __restrict__ W,
                          const float* __restrict__ bias, const float* __restrict__ dis,
                          float* __restrict__ xw_out, float* __restrict__ agg_out, int nN)
{
    const int wave = threadIdx.x >> 6;
    const int lane = threadIdx.x & 63;
    const int n = blockIdx.x * 4 + wave;
    if (n >= nN) return;
    const float* arow = A + (size_t)n * HH;
    float acc = 0.0f;
    #pragma unroll
    for (int k = 0; k < HH; k++) {
        float a = arow[k];
        if (RELU_BIAS) a = fmaxf(a + bias[k], 0.0f);
        acc = fmaf(a, W[k * HH + lane], acc);
    }
    xw_out[(size_t)n * HH + lane] = acc;
    if (WRITE_AGG) {
        const float d = dis[n];
        agg_out[(size_t)n * HH + lane] = acc * d * d;
    }
}

// ---------------- gather: wave per node, 8-deep load pipeline ----------------
template<bool FINAL>
__global__ void gather_kernel(const float* __restrict__ xw, const float* __restrict__ dis,
                              const int* __restrict__ row_ptr, const int* __restrict__ deg,
                              const int* __restrict__ csr_src, const float* __restrict__ csr_dis,
                              float* __restrict__ agg_out,
                              const float* __restrict__ b2, const float* __restrict__ W_lin,
                              const float* __restrict__ b_lin, float* __restrict__ out, int nN)
{
    const int wave = threadIdx.x >> 6;
    const int lane = threadIdx.x & 63;
    const int n = blockIdx.x * 4 + wave;
    if (n >= nN) return;
    const float dn = dis[n];
    float v = xw[(size_t)n * HH + lane] * dn;   // self-loop
    const int start = row_ptr[n];
    const int end   = start + deg[n];
    int i = start;
    for (; i + 8 <= end; i += 8) {
        int   s[8];
        float c[8];
        #pragma unroll
        for (int u = 0; u < 8; u++) { s[u] = csr_src[i + u]; c[u] = csr_dis[i + u]; }
        float xv[8];
        #pragma unroll
        for (int u = 0; u < 8; u++) xv[u] = xw[(size_t)s[u] * HH + lane];
        #pragma unroll
        for (int u = 0; u < 8; u++) v = fmaf(xv[u], c[u], v);
    }
    for (; i < end; i++) {
        v = fmaf(xw[(size_t)csr_src[i] * HH + lane], csr_dis[i], v);
    }
    v *= dn;
    if (FINAL) {
        float val = fmaxf(v + b2[lane], 0.0f) * W_lin[lane];
        #pragma unroll
        for (int off = 32; off > 0; off >>= 1) val += __shfl_down(val, off);
        if (lane == 0) out[n] = val + b_lin[0];
    } else {
        agg_out[(size_t)n * HH + lane] = v;
    }
}

// ---------------- fallback helpers (atomic scatter path) ----------------
__global__ void agg_init_kernel(const float* __restrict__ xw, const float* __restrict__ dis,
                                float* __restrict__ agg, int nN)
{
    size_t i = (size_t)blockIdx.x * 256 + threadIdx.x;
    if (i >= (size_t)nN * HH) return;
    int n = (int)(i >> 6);
    float d = dis[n];
    agg[i] = xw[i] * d * d;
}

__global__ void scatter_kernel(const float* __restrict__ xw, const float* __restrict__ dis,
                               const int* __restrict__ src, const int* __restrict__ dst,
                               float* __restrict__ agg, int nE, int nN)
{
    const int e = blockIdx.x * 4 + (threadIdx.x >> 6);
    const int lane = threadIdx.x & 63;
    if (e >= nE) return;
    int s = src[e], d = dst[e];
    if ((unsigned)s >= (unsigned)nN || (unsigned)d >= (unsigned)nN) return;
    const float coef = dis[s] * dis[d];
    const float v = xw[(size_t)s * HH + lane] * coef;
    atomicAdd(&agg[(size_t)d * HH + lane], v);
}

__global__ void head_kernel(const float* __restrict__ agg, const float* __restrict__ b2,
                            const float* __restrict__ W_lin, const float* __restrict__ b_lin,
                            float* __restrict__ out, int nN)
{
    const int wave = threadIdx.x >> 6;
    const int lane = threadIdx.x & 63;
    const int n = blockIdx.x * 4 + wave;
    if (n >= nN) return;
    float v = fmaxf(agg[(size_t)n * HH + lane] + b2[lane], 0.0f) * W_lin[lane];
    #pragma unroll
    for (int off = 32; off > 0; off >>= 1) v += __shfl_down(v, off);
    if (lane == 0) out[n] = v + b_lin[0];
}

extern "C" void kernel_launch(void* const* d_in, const int* in_sizes, int n_in,
                              void* d_out, int out_size, void* d_ws, size_t ws_size,
                              hipStream_t stream)
{
    const float* x     = (const float*)d_in[0];
    const int*   edge  = (const int*)d_in[1];
    const float* W_ih  = (const float*)d_in[2];
    const float* W_hh  = (const float*)d_in[3];
    const float* b_ih  = (const float*)d_in[4];
    const float* b_hh  = (const float*)d_in[5];
    const float* W1    = (const float*)d_in[6];
    const float* b1    = (const float*)d_in[7];
    const float* W2    = (const float*)d_in[8];
    const float* b2    = (const float*)d_in[9];
    const float* W_lin = (const float*)d_in[10];
    const float* b_lin = (const float*)d_in[11];
    float* out = (float*)d_out;

    const int nN = in_sizes[0] / (WW * FF);   // 100000
    const int nE = in_sizes[1] / 2;           // 1600000
    const int* src = edge;
    const int* dst = edge + nE;

    float* ws = (float*)d_ws;
    const size_t npad = ((size_t)nN + 255) & ~(size_t)255;
    float* dis = ws;                           // [N]
    float* A   = ws + npad;                    // [N,64] (fallback scratch)
    float* B   = A + (size_t)nN * HH;          // [N,64]
    float* C   = B + (size_t)nN * HH;          // [N,64]
    int*   deg_i   = (int*)(C + (size_t)nN * HH);   // [N]
    int*   row_ptr = deg_i + npad;                  // [N]
    int*   cursor  = row_ptr + npad;                // [N]
    int*   csr_src = cursor + npad;                 // [E]
    float* csr_dis = (float*)(csr_src + nE);        // [E]

    const size_t need = (npad + 3 * (size_t)nN * HH + 3 * npad + 2 * (size_t)nE) * 4;
    const bool use_csr = (ws_size >= need);

    const int gN256 = (nN + 255) / 256;
    const int gE256 = (nE + 255) / 256;
    const int gN4   = (nN + 3) / 4;

    if (use_csr) {
        zero_int_kernel<<<gN256, 256, 0, stream>>>(deg_i, nN);
        deg_int_kernel<<<gE256, 256, 0, stream>>>(dst, deg_i, nE, nN);
        dis_from_deg_kernel<<<gN256, 256, 0, stream>>>(deg_i, dis, nN);
        scan_kernel<<<1, 1024, 0, stream>>>(deg_i, row_ptr, cursor, nN);
        place_kernel<<<gE256, 256, 0, stream>>>(src, dst, dis, cursor, csr_src, csr_dis, nE, nN);

        // LSTM + fused xw1 -> B
        lstm_mfma_kernel<<<(nN + 63) / 64, 256, 0, stream>>>(x, W_ih, W_hh, b_ih, b_hh, W1, B, nN);

        gather_kernel<false><<<gN4, 256, 0, stream>>>(B, dis, row_ptr, deg_i, csr_src, csr_dis,
                                                      C, nullptr, nullptr, nullptr, nullptr, nN);
        xw_kernel<true, false><<<gN4, 256, 0, stream>>>(C, W2, b1, dis, B, nullptr, nN);
        gather_kernel<true><<<gN4, 256, 0, stream>>>(B, dis, row_ptr, deg_i, csr_src, csr_dis,
                                                     nullptr, b2, W_lin, b_lin, out, nN);
    } else {
        zero_int_kernel<<<gN256, 256, 0, stream>>>(deg_i, nN);
        deg_int_kernel<<<gE256, 256, 0, stream>>>(dst, deg_i, nE, nN);
        dis_from_deg_kernel<<<gN256, 256, 0, stream>>>(deg_i, dis, nN);

        lstm_mfma_kernel<<<(nN + 63) / 64, 256, 0, stream>>>(x, W_ih, W_hh, b_ih, b_hh, W1, B, nN);

        agg_init_kernel<<<(int)(((size_t)nN * HH + 255) / 256), 256, 0, stream>>>(B, dis, C, nN);
        scatter_kernel<<<(nE + 3) / 4, 256, 0, stream>>>(B, dis, src, dst, C, nE, nN);

        xw_kernel<true, true><<<gN4, 256, 0, stream>>>(C, W2, b1, dis, A, B, nN);
        scatter_kernel<<<(nE + 3) / 4, 256, 0, stream>>>(A, dis, src, dst, B, nE, nN);

        head_kernel<<<gN4, 256, 0, stream>>>(B, b2, W_lin, b_lin, out, nN);
    }
}

// Round 14
// 1055.958 us; speedup vs baseline: 2.1949x; 1.0518x over previous
//
#include <hip/hip_runtime.h>
#include <math.h>

#define WW 32
#define FF 16
#define HH 64

typedef __attribute__((ext_vector_type(8))) short bf16x8;
typedef __attribute__((ext_vector_type(4))) float f32x4;

__device__ __forceinline__ unsigned short bf16h(float f) {   // RNE round
    unsigned int u = __float_as_uint(f);
    unsigned int r = (u + 0x7FFFu + ((u >> 16) & 1u)) >> 16;
    return (unsigned short)r;
}

__device__ __forceinline__ float fexp2(float x) {
#if __has_builtin(__builtin_amdgcn_exp2f)
    return __builtin_amdgcn_exp2f(x);
#else
    return exp2f(x);
#endif
}
__device__ __forceinline__ float frcp(float x) {
#if __has_builtin(__builtin_amdgcn_rcpf)
    return __builtin_amdgcn_rcpf(x);
#else
    return 1.0f / x;
#endif
}
__device__ __forceinline__ float fsig(float v)  { return frcp(1.0f + fexp2(v * -1.44269504f)); }
__device__ __forceinline__ float ftanh(float v) { return fmaf(-2.0f, frcp(1.0f + fexp2(v * 2.88539008f)), 1.0f); }

// trunc-split: hi = trunc-bf16(v), lo = trunc-bf16(v - hi)
__device__ __forceinline__ void tsplit8(const float* v, bf16x8& hi, bf16x8& lo) {
    #pragma unroll
    for (int i = 0; i < 8; i++) {
        unsigned int u = __float_as_uint(v[i]);
        hi[i] = (short)(u >> 16);
        float lf = v[i] - __uint_as_float(u & 0xFFFF0000u);
        lo[i] = (short)(__float_as_uint(lf) >> 16);
    }
}

// ---------------- LSTM via MFMA + FUSED xw1 = h_last @ W1 ----------------
__global__ __launch_bounds__(256, 2) void lstm_mfma_kernel(
    const float* __restrict__ x,      // [N,32,16]
    const float* __restrict__ W_ih,   // [256,16]
    const float* __restrict__ W_hh,   // [256,64]
    const float* __restrict__ b_ih,   // [256]
    const float* __restrict__ b_hh,   // [256]
    const float* __restrict__ W1,     // [64,64]  (xw = h @ W1)
    float* __restrict__ xw_out,       // [N,64]
    int nN)
{
    __shared__ short Zs[2][2][64][64];   // 32768 B
    __shared__ short Xs[2][64][32];      // 8192 B
    const int tid  = threadIdx.x;
    const int lane = tid & 63;
    const int wv   = tid >> 6;
    const int l15  = lane & 15;
    const int g    = lane >> 4;
    const int n0   = blockIdx.x * 64;

    bf16x8 Bh[4][2], Bl[4][2], Bx[4];
    float bias[4];
    #pragma unroll
    for (int gate = 0; gate < 4; gate++) {
        const int j = 64 * gate + 16 * wv + l15;
        bias[gate] = b_ih[j] + b_hh[j];
        #pragma unroll
        for (int q = 0; q < 2; q++) {
            const float* wr = W_hh + j * HH + 32 * q + 8 * g;
            float v[8];
            float4 a = reinterpret_cast<const float4*>(wr)[0];
            float4 b = reinterpret_cast<const float4*>(wr)[1];
            v[0]=a.x; v[1]=a.y; v[2]=a.z; v[3]=a.w; v[4]=b.x; v[5]=b.y; v[6]=b.z; v[7]=b.w;
            tsplit8(v, Bh[gate][q], Bl[gate][q]);
        }
        {
            const float* wr = W_ih + j * FF + 8 * (g & 1);
            float4 a = reinterpret_cast<const float4*>(wr)[0];
            float4 b = reinterpret_cast<const float4*>(wr)[1];
            float v[8] = {a.x,a.y,a.z,a.w,b.x,b.y,b.z,b.w};
            bf16x8 bx;
            #pragma unroll
            for (int i = 0; i < 8; i++) bx[i] = (short)bf16h(v[i]);
            Bx[gate] = bx;
        }
    }

    {
        int4* zz = (int4*)(&Zs[0][0][0][0]);
        #pragma unroll
        for (int c = 0; c < 4; c++) zz[c * 256 + tid] = make_int4(0, 0, 0, 0);
        int gn = n0 + (tid >> 2); if (gn >= nN) gn = nN - 1;
        const float4 xf = *reinterpret_cast<const float4*>(x + (size_t)gn * (WW * FF) + (tid & 3) * 4);
        unsigned int u0 = __float_as_uint(xf.x), u1 = __float_as_uint(xf.y);
        unsigned int u2 = __float_as_uint(xf.z), u3 = __float_as_uint(xf.w);
        short4 hs = make_short4((short)(u0>>16), (short)(u1>>16), (short)(u2>>16), (short)(u3>>16));
        float f0 = xf.x - __uint_as_float(u0 & 0xFFFF0000u);
        float f1 = xf.y - __uint_as_float(u1 & 0xFFFF0000u);
        float f2 = xf.z - __uint_as_float(u2 & 0xFFFF0000u);
        float f3 = xf.w - __uint_as_float(u3 & 0xFFFF0000u);
        short4 ls = make_short4((short)(__float_as_uint(f0)>>16), (short)(__float_as_uint(f1)>>16),
                                (short)(__float_as_uint(f2)>>16), (short)(__float_as_uint(f3)>>16));
        *reinterpret_cast<short4*>(&Xs[0][tid >> 2][(tid & 3) * 4])      = hs;
        *reinterpret_cast<short4*>(&Xs[0][tid >> 2][16 + (tid & 3) * 4]) = ls;
    }
    __syncthreads();

    const char* zbase  = (const char*)Zs;
    char*       zwbase = (char*)Zs;
    const char* xbase  = (const char*)Xs;

    const int aoff0 = l15 * 128 + ((g ^ (l15 & 7)) * 16);
    const int aoff1 = l15 * 128 + (((4 + g) ^ (l15 & 7)) * 16);
    const int xoff  = l15 * 64 + g * 16;
    const int wblk  = 2 * wv + (l15 >> 3);
    const int wsh   = (l15 & 7) * 2;

    f32x4 cst[4] = {{0.f,0.f,0.f,0.f},{0.f,0.f,0.f,0.f},{0.f,0.f,0.f,0.f},{0.f,0.f,0.f,0.f}};

    #pragma unroll 1
    for (int t = 0; t < WW; t++) {
        const int buf = t & 1;

        int gn = n0 + (tid >> 2); if (gn >= nN) gn = nN - 1;
        const int tn = (t + 1 < WW) ? (t + 1) : t;
        const float4 xf = *reinterpret_cast<const float4*>(x + (size_t)gn * (WW * FF) + tn * FF + (tid & 3) * 4);

        #pragma unroll
        for (int rt = 0; rt < 4; rt++) {
            const bf16x8 Ah0 = *reinterpret_cast<const bf16x8*>(zbase + buf*16384 + 0*8192 + rt*2048 + aoff0);
            const bf16x8 Ah1 = *reinterpret_cast<const bf16x8*>(zbase + buf*16384 + 0*8192 + rt*2048 + aoff1);
            const bf16x8 Al0 = *reinterpret_cast<const bf16x8*>(zbase + buf*16384 + 1*8192 + rt*2048 + aoff0);
            const bf16x8 Al1 = *reinterpret_cast<const bf16x8*>(zbase + buf*16384 + 1*8192 + rt*2048 + aoff1);
            const bf16x8 Ax  = *reinterpret_cast<const bf16x8*>(xbase + buf*4096 + rt*1024 + xoff);
            f32x4 acc[4];
            #pragma unroll
            for (int gate = 0; gate < 4; gate++) {
                f32x4 ini = {bias[gate], bias[gate], bias[gate], bias[gate]};
                acc[gate] = ini;
            }
            #pragma unroll
            for (int gate = 0; gate < 4; gate++) {
                acc[gate] = __builtin_amdgcn_mfma_f32_16x16x32_bf16(Ah0, Bh[gate][0], acc[gate], 0, 0, 0);
                acc[gate] = __builtin_amdgcn_mfma_f32_16x16x32_bf16(Al0, Bh[gate][0], acc[gate], 0, 0, 0);
                acc[gate] = __builtin_amdgcn_mfma_f32_16x16x32_bf16(Ah0, Bl[gate][0], acc[gate], 0, 0, 0);
                acc[gate] = __builtin_amdgcn_mfma_f32_16x16x32_bf16(Ah1, Bh[gate][1], acc[gate], 0, 0, 0);
                acc[gate] = __builtin_amdgcn_mfma_f32_16x16x32_bf16(Al1, Bh[gate][1], acc[gate], 0, 0, 0);
                acc[gate] = __builtin_amdgcn_mfma_f32_16x16x32_bf16(Ah1, Bl[gate][1], acc[gate], 0, 0, 0);
                acc[gate] = __builtin_amdgcn_mfma_f32_16x16x32_bf16(Ax,  Bx[gate],    acc[gate], 0, 0, 0);
            }
            #pragma unroll
            for (int r = 0; r < 4; r++) {
                const float ig = fsig(acc[0][r]);
                const float fg = fsig(acc[1][r]);
                const float gg = ftanh(acc[2][r]);
                const float og = fsig(acc[3][r]);
                const float c  = fg * cst[rt][r] + ig * gg;
                cst[rt][r] = c;
                const float h  = og * ftanh(c);
                const int node = 16 * rt + 4 * g + r;
                const int sw   = ((wblk ^ ((4 * g + r) & 7)) * 16) + wsh;
                char* wp = zwbase + (buf ^ 1) * 16384 + node * 128 + sw;
                unsigned int u = __float_as_uint(h);
                *(short*)(wp)        = (short)(u >> 16);
                float lf = h - __uint_as_float(u & 0xFFFF0000u);
                *(short*)(wp + 8192) = (short)(__float_as_uint(lf) >> 16);
            }
        }
        if (t < WW - 1) {
            unsigned int u0 = __float_as_uint(xf.x), u1 = __float_as_uint(xf.y);
            unsigned int u2 = __float_as_uint(xf.z), u3 = __float_as_uint(xf.w);
            short4 hs = make_short4((short)(u0>>16), (short)(u1>>16), (short)(u2>>16), (short)(u3>>16));
            float f0 = xf.x - __uint_as_float(u0 & 0xFFFF0000u);
            float f1 = xf.y - __uint_as_float(u1 & 0xFFFF0000u);
            float f2 = xf.z - __uint_as_float(u2 & 0xFFFF0000u);
            float f3 = xf.w - __uint_as_float(u3 & 0xFFFF0000u);
            short4 ls = make_short4((short)(__float_as_uint(f0)>>16), (short)(__float_as_uint(f1)>>16),
                                    (short)(__float_as_uint(f2)>>16), (short)(__float_as_uint(f3)>>16));
            *reinterpret_cast<short4*>(&Xs[buf ^ 1][tid >> 2][(tid & 3) * 4])      = hs;
            *reinterpret_cast<short4*>(&Xs[buf ^ 1][tid >> 2][16 + (tid & 3) * 4]) = ls;
        }
        __syncthreads();
    }

    // ---- fused xw = h_last @ W1 (h_last in Zs buf 0) ----
    bf16x8 W1h[2], W1l[2];
    #pragma unroll
    for (int q = 0; q < 2; q++) {
        float v[8];
        #pragma unroll
        for (int i = 0; i < 8; i++)
            v[i] = W1[(32 * q + 8 * g + i) * HH + 16 * wv + l15];
        tsplit8(v, W1h[q], W1l[q]);
    }
    #pragma unroll
    for (int rt = 0; rt < 4; rt++) {
        const bf16x8 Ah0 = *reinterpret_cast<const bf16x8*>(zbase + 0*8192 + rt*2048 + aoff0);
        const bf16x8 Ah1 = *reinterpret_cast<const bf16x8*>(zbase + 0*8192 + rt*2048 + aoff1);
        const bf16x8 Al0 = *reinterpret_cast<const bf16x8*>(zbase + 1*8192 + rt*2048 + aoff0);
        const bf16x8 Al1 = *reinterpret_cast<const bf16x8*>(zbase + 1*8192 + rt*2048 + aoff1);
        f32x4 acc = {0.f, 0.f, 0.f, 0.f};
        acc = __builtin_amdgcn_mfma_f32_16x16x32_bf16(Ah0, W1h[0], acc, 0, 0, 0);
        acc = __builtin_amdgcn_mfma_f32_16x16x32_bf16(Al0, W1h[0], acc, 0, 0, 0);
        acc = __builtin_amdgcn_mfma_f32_16x16x32_bf16(Ah0, W1l[0], acc, 0, 0, 0);
        acc = __builtin_amdgcn_mfma_f32_16x16x32_bf16(Ah1, W1h[1], acc, 0, 0, 0);
        acc = __builtin_amdgcn_mfma_f32_16x16x32_bf16(Al1, W1h[1], acc, 0, 0, 0);
        acc = __builtin_amdgcn_mfma_f32_16x16x32_bf16(Ah1, W1l[1], acc, 0, 0, 0);
        #pragma unroll
        for (int r = 0; r < 4; r++) {
            const int node = n0 + 16 * rt + 4 * g + r;
            if (node < nN) xw_out[(size_t)node * HH + 16 * wv + l15] = acc[r];
        }
    }
}

// ---------------- CSR build ----------------
__global__ void zero_int_kernel(int* __restrict__ p, int n) {
    int i = blockIdx.x * 256 + threadIdx.x;
    if (i < n) p[i] = 0;
}

__global__ void deg_int_kernel(const int* __restrict__ dst, int* __restrict__ deg, int nE, int nN) {
    int e = blockIdx.x * 256 + threadIdx.x;
    if (e < nE) {
        int d = dst[e];
        if ((unsigned)d < (unsigned)nN) atomicAdd(&deg[d], 1);
    }
}

__global__ void dis_from_deg_kernel(const int* __restrict__ deg, float* __restrict__ dis, int nN) {
    int i = blockIdx.x * 256 + threadIdx.x;
    if (i < nN) dis[i] = rsqrtf((float)deg[i] + 1.0f);
}

__global__ __launch_bounds__(1024) void scan_kernel(const int* __restrict__ deg,
                                                    int* __restrict__ row_ptr,
                                                    int* __restrict__ cursor, int nN)
{
    __shared__ int wsum[16];
    const int tid  = threadIdx.x;
    const int lane = tid & 63;
    const int wv   = tid >> 6;
    const int chunk = (nN + 1023) / 1024;
    const int s = tid * chunk;
    const int e = min(s + chunk, nN);
    int sum = 0;
    for (int i = s; i < e; i++) sum += deg[i];

    int inc = sum;
    #pragma unroll
    for (int off = 1; off < 64; off <<= 1) {
        int n = __shfl_up(inc, off);
        if (lane >= off) inc += n;
    }
    if (lane == 63) wsum[wv] = inc;
    __syncthreads();
    if (wv == 0) {
        int w = (lane < 16) ? wsum[lane] : 0;
        int winc = w;
        #pragma unroll
        for (int off = 1; off < 16; off <<= 1) {
            int n = __shfl_up(winc, off);
            if (lane >= off) winc += n;
        }
        if (lane < 16) wsum[lane] = winc - w;
    }
    __syncthreads();
    int acc = inc - sum + wsum[wv];
    for (int i = s; i < e; i++) {
        const int d = deg[i];
        row_ptr[i] = acc;
        cursor[i]  = acc;
        acc += d;
    }
}

__global__ void place_kernel(const int* __restrict__ src, const int* __restrict__ dst,
                             const float* __restrict__ dis, int* __restrict__ cursor,
                             int* __restrict__ csr_src, float* __restrict__ csr_dis,
                             int nE, int nN)
{
    int e = blockIdx.x * 256 + threadIdx.x;
    if (e >= nE) return;
    int s = src[e], d = dst[e];
    if ((unsigned)s >= (unsigned)nN || (unsigned)d >= (unsigned)nN) return;
    int pos = atomicAdd(&cursor[d], 1);
    csr_src[pos] = s;
    csr_dis[pos] = dis[s];
}

// ---------------- xw = act(in) @ W (fallback path only) ----------------
template<bool RELU_BIAS, bool WRITE_AGG>
__global__ void xw_kernel(const float* __restrict__ A, const float* __restrict__ W,
                          const float* __restrict__ bias, const float* __restrict__ dis,
                          float* __restrict__ xw_out, float* __restrict__ agg_out, int nN)
{
    const int wave = threadIdx.x >> 6;
    const int lane = threadIdx.x & 63;
    const int n = blockIdx.x * 4 + wave;
    if (n >= nN) return;
    const float* arow = A + (size_t)n * HH;
    float acc = 0.0f;
    #pragma unroll
    for (int k = 0; k < HH; k++) {
        float a = arow[k];
        if (RELU_BIAS) a = fmaxf(a + bias[k], 0.0f);
        acc = fmaf(a, W[k * HH + lane], acc);
    }
    xw_out[(size_t)n * HH + lane] = acc;
    if (WRITE_AGG) {
        const float d = dis[n];
        agg_out[(size_t)n * HH + lane] = acc * d * d;
    }
}

// ---------------- gather1 + FUSED xw2: agg1 -> relu(+b1) -> @W2 ----------------
// Wave holds the full agg1 row (one elem/lane); xw2 row computed in-wave via
// 64 shuffle-broadcasts + W2 column loads (wave-uniform k -> L1-resident).
// Same k-order as xw_kernel -> bitwise-identical result.
__global__ void gather_xw_kernel(const float* __restrict__ xw, const float* __restrict__ dis,
                                 const int* __restrict__ row_ptr, const int* __restrict__ deg,
                                 const int* __restrict__ csr_src, const float* __restrict__ csr_dis,
                                 const float* __restrict__ b1, const float* __restrict__ W2,
                                 float* __restrict__ xw2_out, int nN)
{
    const int wave = threadIdx.x >> 6;
    const int lane = threadIdx.x & 63;
    const int n = blockIdx.x * 4 + wave;
    if (n >= nN) return;
    const float dn = dis[n];
    float v = xw[(size_t)n * HH + lane] * dn;   // self-loop
    const int start = row_ptr[n];
    const int end   = start + deg[n];
    int i = start;
    for (; i + 8 <= end; i += 8) {
        int   s[8];
        float c[8];
        #pragma unroll
        for (int u = 0; u < 8; u++) { s[u] = csr_src[i + u]; c[u] = csr_dis[i + u]; }
        float xv[8];
        #pragma unroll
        for (int u = 0; u < 8; u++) xv[u] = xw[(size_t)s[u] * HH + lane];
        #pragma unroll
        for (int u = 0; u < 8; u++) v = fmaf(xv[u], c[u], v);
    }
    for (; i < end; i++) {
        v = fmaf(xw[(size_t)csr_src[i] * HH + lane], csr_dis[i], v);
    }
    v *= dn;
    // fused xw2 = relu(agg1 + b1) @ W2
    const float a = fmaxf(v + b1[lane], 0.0f);
    float acc = 0.0f;
    #pragma unroll 8
    for (int k = 0; k < HH; k++) {
        const float ak = __shfl(a, k);
        acc = fmaf(ak, W2[k * HH + lane], acc);
    }
    xw2_out[(size_t)n * HH + lane] = acc;
}

// ---------------- gather2 + head ----------------
__global__ void gather_head_kernel(const float* __restrict__ xw, const float* __restrict__ dis,
                                   const int* __restrict__ row_ptr, const int* __restrict__ deg,
                                   const int* __restrict__ csr_src, const float* __restrict__ csr_dis,
                                   const float* __restrict__ b2, const float* __restrict__ W_lin,
                                   const float* __restrict__ b_lin, float* __restrict__ out, int nN)
{
    const int wave = threadIdx.x >> 6;
    const int lane = threadIdx.x & 63;
    const int n = blockIdx.x * 4 + wave;
    if (n >= nN) return;
    const float dn = dis[n];
    float v = xw[(size_t)n * HH + lane] * dn;   // self-loop
    const int start = row_ptr[n];
    const int end   = start + deg[n];
    int i = start;
    for (; i + 8 <= end; i += 8) {
        int   s[8];
        float c[8];
        #pragma unroll
        for (int u = 0; u < 8; u++) { s[u] = csr_src[i + u]; c[u] = csr_dis[i + u]; }
        float xv[8];
        #pragma unroll
        for (int u = 0; u < 8; u++) xv[u] = xw[(size_t)s[u] * HH + lane];
        #pragma unroll
        for (int u = 0; u < 8; u++) v = fmaf(xv[u], c[u], v);
    }
    for (; i < end; i++) {
        v = fmaf(xw[(size_t)csr_src[i] * HH + lane], csr_dis[i], v);
    }
    v *= dn;
    float val = fmaxf(v + b2[lane], 0.0f) * W_lin[lane];
    #pragma unroll
    for (int off = 32; off > 0; off >>= 1) val += __shfl_down(val, off);
    if (lane == 0) out[n] = val + b_lin[0];
}

// ---------------- fallback helpers (atomic scatter path) ----------------
__global__ void agg_init_kernel(const float* __restrict__ xw, const float* __restrict__ dis,
                                float* __restrict__ agg, int nN)
{
    size_t i = (size_t)blockIdx.x * 256 + threadIdx.x;
    if (i >= (size_t)nN * HH) return;
    int n = (int)(i >> 6);
    float d = dis[n];
    agg[i] = xw[i] * d * d;
}

__global__ void scatter_kernel(const float* __restrict__ xw, const float* __restrict__ dis,
                               const int* __restrict__ src, const int* __restrict__ dst,
                               float* __restrict__ agg, int nE, int nN)
{
    const int e = blockIdx.x * 4 + (threadIdx.x >> 6);
    const int lane = threadIdx.x & 63;
    if (e >= nE) return;
    int s = src[e], d = dst[e];
    if ((unsigned)s >= (unsigned)nN || (unsigned)d >= (unsigned)nN) return;
    const float coef = dis[s] * dis[d];
    const float v = xw[(size_t)s * HH + lane] * coef;
    atomicAdd(&agg[(size_t)d * HH + lane], v);
}

__global__ void head_kernel(const float* __restrict__ agg, const float* __restrict__ b2,
                            const float* __restrict__ W_lin, const float* __restrict__ b_lin,
                            float* __restrict__ out, int nN)
{
    const int wave = threadIdx.x >> 6;
    const int lane = threadIdx.x & 63;
    const int n = blockIdx.x * 4 + wave;
    if (n >= nN) return;
    float v = fmaxf(agg[(size_t)n * HH + lane] + b2[lane], 0.0f) * W_lin[lane];
    #pragma unroll
    for (int off = 32; off > 0; off >>= 1) v += __shfl_down(v, off);
    if (lane == 0) out[n] = v + b_lin[0];
}

extern "C" void kernel_launch(void* const* d_in, const int* in_sizes, int n_in,
                              void* d_out, int out_size, void* d_ws, size_t ws_size,
                              hipStream_t stream)
{
    const float* x     = (const float*)d_in[0];
    const int*   edge  = (const int*)d_in[1];
    const float* W_ih  = (const float*)d_in[2];
    const float* W_hh  = (const float*)d_in[3];
    const float* b_ih  = (const float*)d_in[4];
    const float* b_hh  = (const float*)d_in[5];
    const float* W1    = (const float*)d_in[6];
    const float* b1    = (const float*)d_in[7];
    const float* W2    = (const float*)d_in[8];
    const float* b2    = (const float*)d_in[9];
    const float* W_lin = (const float*)d_in[10];
    const float* b_lin = (const float*)d_in[11];
    float* out = (float*)d_out;

    const int nN = in_sizes[0] / (WW * FF);   // 100000
    const int nE = in_sizes[1] / 2;           // 1600000
    const int* src = edge;
    const int* dst = edge + nE;

    float* ws = (float*)d_ws;
    const size_t npad = ((size_t)nN + 255) & ~(size_t)255;
    float* dis = ws;                           // [N]
    float* A   = ws + npad;                    // [N,64]
    float* B   = A + (size_t)nN * HH;          // [N,64]
    float* C   = B + (size_t)nN * HH;          // [N,64] (fallback only)
    int*   deg_i   = (int*)(C + (size_t)nN * HH);   // [N]
    int*   row_ptr = deg_i + npad;                  // [N]
    int*   cursor  = row_ptr + npad;                // [N]
    int*   csr_src = cursor + npad;                 // [E]
    float* csr_dis = (float*)(csr_src + nE);        // [E]

    const size_t need = (npad + 3 * (size_t)nN * HH + 3 * npad + 2 * (size_t)nE) * 4;
    const bool use_csr = (ws_size >= need);

    const int gN256 = (nN + 255) / 256;
    const int gE256 = (nE + 255) / 256;
    const int gN4   = (nN + 3) / 4;

    if (use_csr) {
        zero_int_kernel<<<gN256, 256, 0, stream>>>(deg_i, nN);
        deg_int_kernel<<<gE256, 256, 0, stream>>>(dst, deg_i, nE, nN);
        dis_from_deg_kernel<<<gN256, 256, 0, stream>>>(deg_i, dis, nN);
        scan_kernel<<<1, 1024, 0, stream>>>(deg_i, row_ptr, cursor, nN);
        place_kernel<<<gE256, 256, 0, stream>>>(src, dst, dis, cursor, csr_src, csr_dis, nE, nN);

        // LSTM + fused xw1 -> B
        lstm_mfma_kernel<<<(nN + 63) / 64, 256, 0, stream>>>(x, W_ih, W_hh, b_ih, b_hh, W1, B, nN);

        // gather1 + fused xw2 -> A ; gather2 + head -> out
        gather_xw_kernel<<<gN4, 256, 0, stream>>>(B, dis, row_ptr, deg_i, csr_src, csr_dis,
                                                  b1, W2, A, nN);
        gather_head_kernel<<<gN4, 256, 0, stream>>>(A, dis, row_ptr, deg_i, csr_src, csr_dis,
                                                    b2, W_lin, b_lin, out, nN);
    } else {
        zero_int_kernel<<<gN256, 256, 0, stream>>>(deg_i, nN);
        deg_int_kernel<<<gE256, 256, 0, stream>>>(dst, deg_i, nE, nN);
        dis_from_deg_kernel<<<gN256, 256, 0, stream>>>(deg_i, dis, nN);

        lstm_mfma_kernel<<<(nN + 63) / 64, 256, 0, stream>>>(x, W_ih, W_hh, b_ih, b_hh, W1, B, nN);

        agg_init_kernel<<<(int)(((size_t)nN * HH + 255) / 256), 256, 0, stream>>>(B, dis, C, nN);
        scatter_kernel<<<(nE + 3) / 4, 256, 0, stream>>>(B, dis, src, dst, C, nE, nN);

        xw_kernel<true, true><<<gN4, 256, 0, stream>>>(C, W2, b1, dis, A, B, nN);
        scatter_kernel<<<(nE + 3) / 4, 256, 0, stream>>>(A, dis, src, dst, B, nE, nN);

        head_kernel<<<gN4, 256, 0, stream>>>(B, b2, W_lin, b_lin, out, nN);
    }
}

// Round 15
// 1033.818 us; speedup vs baseline: 2.2419x; 1.0214x over previous
//
#include <hip/hip_runtime.h>
#include <math.h>

#define WW 32
#define FF 16
#define HH 64

typedef __attribute__((ext_vector_type(8))) short bf16x8;
typedef __attribute__((ext_vector_type(4))) float f32x4;
typedef _Float16 half_t;

__device__ __forceinline__ unsigned short bf16h(float f) {   // RNE round
    unsigned int u = __float_as_uint(f);
    unsigned int r = (u + 0x7FFFu + ((u >> 16) & 1u)) >> 16;
    return (unsigned short)r;
}

__device__ __forceinline__ float fexp2(float x) {
#if __has_builtin(__builtin_amdgcn_exp2f)
    return __builtin_amdgcn_exp2f(x);
#else
    return exp2f(x);
#endif
}
__device__ __forceinline__ float frcp(float x) {
#if __has_builtin(__builtin_amdgcn_rcpf)
    return __builtin_amdgcn_rcpf(x);
#else
    return 1.0f / x;
#endif
}
__device__ __forceinline__ float fsig(float v)  { return frcp(1.0f + fexp2(v * -1.44269504f)); }
__device__ __forceinline__ float ftanh(float v) { return fmaf(-2.0f, frcp(1.0f + fexp2(v * 2.88539008f)), 1.0f); }

// trunc-split: hi = trunc-bf16(v), lo = trunc-bf16(v - hi)
__device__ __forceinline__ void tsplit8(const float* v, bf16x8& hi, bf16x8& lo) {
    #pragma unroll
    for (int i = 0; i < 8; i++) {
        unsigned int u = __float_as_uint(v[i]);
        hi[i] = (short)(u >> 16);
        float lf = v[i] - __uint_as_float(u & 0xFFFF0000u);
        lo[i] = (short)(__float_as_uint(lf) >> 16);
    }
}

// ---------------- LSTM via MFMA + FUSED xw1 = h_last @ W1 (fp16 out) ----------------
__global__ __launch_bounds__(256, 2) void lstm_mfma_kernel(
    const float* __restrict__ x,      // [N,32,16]
    const float* __restrict__ W_ih,   // [256,16]
    const float* __restrict__ W_hh,   // [256,64]
    const float* __restrict__ b_ih,   // [256]
    const float* __restrict__ b_hh,   // [256]
    const float* __restrict__ W1,     // [64,64]  (xw = h @ W1)
    half_t* __restrict__ xw_out,      // [N,64] fp16
    int nN)
{
    __shared__ short Zs[2][2][64][64];   // 32768 B
    __shared__ short Xs[2][64][32];      // 8192 B
    const int tid  = threadIdx.x;
    const int lane = tid & 63;
    const int wv   = tid >> 6;
    const int l15  = lane & 15;
    const int g    = lane >> 4;
    const int n0   = blockIdx.x * 64;

    bf16x8 Bh[4][2], Bl[4][2], Bx[4];
    float bias[4];
    #pragma unroll
    for (int gate = 0; gate < 4; gate++) {
        const int j = 64 * gate + 16 * wv + l15;
        bias[gate] = b_ih[j] + b_hh[j];
        #pragma unroll
        for (int q = 0; q < 2; q++) {
            const float* wr = W_hh + j * HH + 32 * q + 8 * g;
            float v[8];
            float4 a = reinterpret_cast<const float4*>(wr)[0];
            float4 b = reinterpret_cast<const float4*>(wr)[1];
            v[0]=a.x; v[1]=a.y; v[2]=a.z; v[3]=a.w; v[4]=b.x; v[5]=b.y; v[6]=b.z; v[7]=b.w;
            tsplit8(v, Bh[gate][q], Bl[gate][q]);
        }
        {
            const float* wr = W_ih + j * FF + 8 * (g & 1);
            float4 a = reinterpret_cast<const float4*>(wr)[0];
            float4 b = reinterpret_cast<const float4*>(wr)[1];
            float v[8] = {a.x,a.y,a.z,a.w,b.x,b.y,b.z,b.w};
            bf16x8 bx;
            #pragma unroll
            for (int i = 0; i < 8; i++) bx[i] = (short)bf16h(v[i]);
            Bx[gate] = bx;
        }
    }

    {
        int4* zz = (int4*)(&Zs[0][0][0][0]);
        #pragma unroll
        for (int c = 0; c < 4; c++) zz[c * 256 + tid] = make_int4(0, 0, 0, 0);
        int gn = n0 + (tid >> 2); if (gn >= nN) gn = nN - 1;
        const float4 xf = *reinterpret_cast<const float4*>(x + (size_t)gn * (WW * FF) + (tid & 3) * 4);
        unsigned int u0 = __float_as_uint(xf.x), u1 = __float_as_uint(xf.y);
        unsigned int u2 = __float_as_uint(xf.z), u3 = __float_as_uint(xf.w);
        short4 hs = make_short4((short)(u0>>16), (short)(u1>>16), (short)(u2>>16), (short)(u3>>16));
        float f0 = xf.x - __uint_as_float(u0 & 0xFFFF0000u);
        float f1 = xf.y - __uint_as_float(u1 & 0xFFFF0000u);
        float f2 = xf.z - __uint_as_float(u2 & 0xFFFF0000u);
        float f3 = xf.w - __uint_as_float(u3 & 0xFFFF0000u);
        short4 ls = make_short4((short)(__float_as_uint(f0)>>16), (short)(__float_as_uint(f1)>>16),
                                (short)(__float_as_uint(f2)>>16), (short)(__float_as_uint(f3)>>16));
        *reinterpret_cast<short4*>(&Xs[0][tid >> 2][(tid & 3) * 4])      = hs;
        *reinterpret_cast<short4*>(&Xs[0][tid >> 2][16 + (tid & 3) * 4]) = ls;
    }
    __syncthreads();

    const char* zbase  = (const char*)Zs;
    char*       zwbase = (char*)Zs;
    const char* xbase  = (const char*)Xs;

    const int aoff0 = l15 * 128 + ((g ^ (l15 & 7)) * 16);
    const int aoff1 = l15 * 128 + (((4 + g) ^ (l15 & 7)) * 16);
    const int xoff  = l15 * 64 + g * 16;
    const int wblk  = 2 * wv + (l15 >> 3);
    const int wsh   = (l15 & 7) * 2;

    f32x4 cst[4] = {{0.f,0.f,0.f,0.f},{0.f,0.f,0.f,0.f},{0.f,0.f,0.f,0.f},{0.f,0.f,0.f,0.f}};

    #pragma unroll 1
    for (int t = 0; t < WW; t++) {
        const int buf = t & 1;

        int gn = n0 + (tid >> 2); if (gn >= nN) gn = nN - 1;
        const int tn = (t + 1 < WW) ? (t + 1) : t;
        const float4 xf = *reinterpret_cast<const float4*>(x + (size_t)gn * (WW * FF) + tn * FF + (tid & 3) * 4);

        #pragma unroll
        for (int rt = 0; rt < 4; rt++) {
            const bf16x8 Ah0 = *reinterpret_cast<const bf16x8*>(zbase + buf*16384 + 0*8192 + rt*2048 + aoff0);
            const bf16x8 Ah1 = *reinterpret_cast<const bf16x8*>(zbase + buf*16384 + 0*8192 + rt*2048 + aoff1);
            const bf16x8 Al0 = *reinterpret_cast<const bf16x8*>(zbase + buf*16384 + 1*8192 + rt*2048 + aoff0);
            const bf16x8 Al1 = *reinterpret_cast<const bf16x8*>(zbase + buf*16384 + 1*8192 + rt*2048 + aoff1);
            const bf16x8 Ax  = *reinterpret_cast<const bf16x8*>(xbase + buf*4096 + rt*1024 + xoff);
            f32x4 acc[4];
            #pragma unroll
            for (int gate = 0; gate < 4; gate++) {
                f32x4 ini = {bias[gate], bias[gate], bias[gate], bias[gate]};
                acc[gate] = ini;
            }
            #pragma unroll
            for (int gate = 0; gate < 4; gate++) {
                acc[gate] = __builtin_amdgcn_mfma_f32_16x16x32_bf16(Ah0, Bh[gate][0], acc[gate], 0, 0, 0);
                acc[gate] = __builtin_amdgcn_mfma_f32_16x16x32_bf16(Al0, Bh[gate][0], acc[gate], 0, 0, 0);
                acc[gate] = __builtin_amdgcn_mfma_f32_16x16x32_bf16(Ah0, Bl[gate][0], acc[gate], 0, 0, 0);
                acc[gate] = __builtin_amdgcn_mfma_f32_16x16x32_bf16(Ah1, Bh[gate][1], acc[gate], 0, 0, 0);
                acc[gate] = __builtin_amdgcn_mfma_f32_16x16x32_bf16(Al1, Bh[gate][1], acc[gate], 0, 0, 0);
                acc[gate] = __builtin_amdgcn_mfma_f32_16x16x32_bf16(Ah1, Bl[gate][1], acc[gate], 0, 0, 0);
                acc[gate] = __builtin_amdgcn_mfma_f32_16x16x32_bf16(Ax,  Bx[gate],    acc[gate], 0, 0, 0);
            }
            #pragma unroll
            for (int r = 0; r < 4; r++) {
                const float ig = fsig(acc[0][r]);
                const float fg = fsig(acc[1][r]);
                const float gg = ftanh(acc[2][r]);
                const float og = fsig(acc[3][r]);
                const float c  = fg * cst[rt][r] + ig * gg;
                cst[rt][r] = c;
                const float h  = og * ftanh(c);
                const int node = 16 * rt + 4 * g + r;
                const int sw   = ((wblk ^ ((4 * g + r) & 7)) * 16) + wsh;
                char* wp = zwbase + (buf ^ 1) * 16384 + node * 128 + sw;
                unsigned int u = __float_as_uint(h);
                *(short*)(wp)        = (short)(u >> 16);
                float lf = h - __uint_as_float(u & 0xFFFF0000u);
                *(short*)(wp + 8192) = (short)(__float_as_uint(lf) >> 16);
            }
        }
        if (t < WW - 1) {
            unsigned int u0 = __float_as_uint(xf.x), u1 = __float_as_uint(xf.y);
            unsigned int u2 = __float_as_uint(xf.z), u3 = __float_as_uint(xf.w);
            short4 hs = make_short4((short)(u0>>16), (short)(u1>>16), (short)(u2>>16), (short)(u3>>16));
            float f0 = xf.x - __uint_as_float(u0 & 0xFFFF0000u);
            float f1 = xf.y - __uint_as_float(u1 & 0xFFFF0000u);
            float f2 = xf.z - __uint_as_float(u2 & 0xFFFF0000u);
            float f3 = xf.w - __uint_as_float(u3 & 0xFFFF0000u);
            short4 ls = make_short4((short)(__float_as_uint(f0)>>16), (short)(__float_as_uint(f1)>>16),
                                    (short)(__float_as_uint(f2)>>16), (short)(__float_as_uint(f3)>>16));
            *reinterpret_cast<short4*>(&Xs[buf ^ 1][tid >> 2][(tid & 3) * 4])      = hs;
            *reinterpret_cast<short4*>(&Xs[buf ^ 1][tid >> 2][16 + (tid & 3) * 4]) = ls;
        }
        __syncthreads();
    }

    // ---- fused xw = h_last @ W1 (h_last in Zs buf 0), fp16 store ----
    bf16x8 W1h[2], W1l[2];
    #pragma unroll
    for (int q = 0; q < 2; q++) {
        float v[8];
        #pragma unroll
        for (int i = 0; i < 8; i++)
            v[i] = W1[(32 * q + 8 * g + i) * HH + 16 * wv + l15];
        tsplit8(v, W1h[q], W1l[q]);
    }
    #pragma unroll
    for (int rt = 0; rt < 4; rt++) {
        const bf16x8 Ah0 = *reinterpret_cast<const bf16x8*>(zbase + 0*8192 + rt*2048 + aoff0);
        const bf16x8 Ah1 = *reinterpret_cast<const bf16x8*>(zbase + 0*8192 + rt*2048 + aoff1);
        const bf16x8 Al0 = *reinterpret_cast<const bf16x8*>(zbase + 1*8192 + rt*2048 + aoff0);
        const bf16x8 Al1 = *reinterpret_cast<const bf16x8*>(zbase + 1*8192 + rt*2048 + aoff1);
        f32x4 acc = {0.f, 0.f, 0.f, 0.f};
        acc = __builtin_amdgcn_mfma_f32_16x16x32_bf16(Ah0, W1h[0], acc, 0, 0, 0);
        acc = __builtin_amdgcn_mfma_f32_16x16x32_bf16(Al0, W1h[0], acc, 0, 0, 0);
        acc = __builtin_amdgcn_mfma_f32_16x16x32_bf16(Ah0, W1l[0], acc, 0, 0, 0);
        acc = __builtin_amdgcn_mfma_f32_16x16x32_bf16(Ah1, W1h[1], acc, 0, 0, 0);
        acc = __builtin_amdgcn_mfma_f32_16x16x32_bf16(Al1, W1h[1], acc, 0, 0, 0);
        acc = __builtin_amdgcn_mfma_f32_16x16x32_bf16(Ah1, W1l[1], acc, 0, 0, 0);
        #pragma unroll
        for (int r = 0; r < 4; r++) {
            const int node = n0 + 16 * rt + 4 * g + r;
            if (node < nN) xw_out[(size_t)node * HH + 16 * wv + l15] = (half_t)acc[r];
        }
    }
}

// ---------------- CSR build ----------------
__global__ void zero_int_kernel(int* __restrict__ p, int n) {
    int i = blockIdx.x * 256 + threadIdx.x;
    if (i < n) p[i] = 0;
}

__global__ void deg_int_kernel(const int* __restrict__ dst, int* __restrict__ deg, int nE, int nN) {
    int e = blockIdx.x * 256 + threadIdx.x;
    if (e < nE) {
        int d = dst[e];
        if ((unsigned)d < (unsigned)nN) atomicAdd(&deg[d], 1);
    }
}

__global__ void dis_from_deg_kernel(const int* __restrict__ deg, float* __restrict__ dis, int nN) {
    int i = blockIdx.x * 256 + threadIdx.x;
    if (i < nN) dis[i] = rsqrtf((float)deg[i] + 1.0f);
}

__global__ __launch_bounds__(1024) void scan_kernel(const int* __restrict__ deg,
                                                    int* __restrict__ row_ptr,
                                                    int* __restrict__ cursor, int nN)
{
    __shared__ int wsum[16];
    const int tid  = threadIdx.x;
    const int lane = tid & 63;
    const int wv   = tid >> 6;
    const int chunk = (nN + 1023) / 1024;
    const int s = tid * chunk;
    const int e = min(s + chunk, nN);
    int sum = 0;
    for (int i = s; i < e; i++) sum += deg[i];

    int inc = sum;
    #pragma unroll
    for (int off = 1; off < 64; off <<= 1) {
        int n = __shfl_up(inc, off);
        if (lane >= off) inc += n;
    }
    if (lane == 63) wsum[wv] = inc;
    __syncthreads();
    if (wv == 0) {
        int w = (lane < 16) ? wsum[lane] : 0;
        int winc = w;
        #pragma unroll
        for (int off = 1; off < 16; off <<= 1) {
            int n = __shfl_up(winc, off);
            if (lane >= off) winc += n;
        }
        if (lane < 16) wsum[lane] = winc - w;
    }
    __syncthreads();
    int acc = inc - sum + wsum[wv];
    for (int i = s; i < e; i++) {
        const int d = deg[i];
        row_ptr[i] = acc;
        cursor[i]  = acc;
        acc += d;
    }
}

__global__ void place_kernel(const int* __restrict__ src, const int* __restrict__ dst,
                             const float* __restrict__ dis, int* __restrict__ cursor,
                             int* __restrict__ csr_src, float* __restrict__ csr_dis,
                             int nE, int nN)
{
    int e = blockIdx.x * 256 + threadIdx.x;
    if (e >= nE) return;
    int s = src[e], d = dst[e];
    if ((unsigned)s >= (unsigned)nN || (unsigned)d >= (unsigned)nN) return;
    int pos = atomicAdd(&cursor[d], 1);
    csr_src[pos] = s;
    csr_dis[pos] = dis[s];
}

// ---------------- gather1 + FUSED xw2 (fp16 in, fp16 out) ----------------
__global__ void gather_xw_kernel(const half_t* __restrict__ xw, const float* __restrict__ dis,
                                 const int* __restrict__ row_ptr, const int* __restrict__ deg,
                                 const int* __restrict__ csr_src, const float* __restrict__ csr_dis,
                                 const float* __restrict__ b1, const float* __restrict__ W2,
                                 half_t* __restrict__ xw2_out, int nN)
{
    const int wave = threadIdx.x >> 6;
    const int lane = threadIdx.x & 63;
    const int n = blockIdx.x * 4 + wave;
    if (n >= nN) return;
    const float dn = dis[n];
    float v = (float)xw[(size_t)n * HH + lane] * dn;   // self-loop
    const int start = row_ptr[n];
    const int end   = start + deg[n];
    int i = start;
    for (; i + 8 <= end; i += 8) {
        int   s[8];
        float c[8];
        #pragma unroll
        for (int u = 0; u < 8; u++) { s[u] = csr_src[i + u]; c[u] = csr_dis[i + u]; }
        float xv[8];
        #pragma unroll
        for (int u = 0; u < 8; u++) xv[u] = (float)xw[(size_t)s[u] * HH + lane];
        #pragma unroll
        for (int u = 0; u < 8; u++) v = fmaf(xv[u], c[u], v);
    }
    for (; i < end; i++) {
        v = fmaf((float)xw[(size_t)csr_src[i] * HH + lane], csr_dis[i], v);
    }
    v *= dn;
    // fused xw2 = relu(agg1 + b1) @ W2
    const float a = fmaxf(v + b1[lane], 0.0f);
    float acc = 0.0f;
    #pragma unroll 8
    for (int k = 0; k < HH; k++) {
        const float ak = __shfl(a, k);
        acc = fmaf(ak, W2[k * HH + lane], acc);
    }
    xw2_out[(size_t)n * HH + lane] = (half_t)acc;
}

// ---------------- gather2 + head (fp16 in) ----------------
__global__ void gather_head_kernel(const half_t* __restrict__ xw, const float* __restrict__ dis,
                                   const int* __restrict__ row_ptr, const int* __restrict__ deg,
                                   const int* __restrict__ csr_src, const float* __restrict__ csr_dis,
                                   const float* __restrict__ b2, const float* __restrict__ W_lin,
                                   const float* __restrict__ b_lin, float* __restrict__ out, int nN)
{
    const int wave = threadIdx.x >> 6;
    const int lane = threadIdx.x & 63;
    const int n = blockIdx.x * 4 + wave;
    if (n >= nN) return;
    const float dn = dis[n];
    float v = (float)xw[(size_t)n * HH + lane] * dn;   // self-loop
    const int start = row_ptr[n];
    const int end   = start + deg[n];
    int i = start;
    for (; i + 8 <= end; i += 8) {
        int   s[8];
        float c[8];
        #pragma unroll
        for (int u = 0; u < 8; u++) { s[u] = csr_src[i + u]; c[u] = csr_dis[i + u]; }
        float xv[8];
        #pragma unroll
        for (int u = 0; u < 8; u++) xv[u] = (float)xw[(size_t)s[u] * HH + lane];
        #pragma unroll
        for (int u = 0; u < 8; u++) v = fmaf(xv[u], c[u], v);
    }
    for (; i < end; i++) {
        v = fmaf((float)xw[(size_t)csr_src[i] * HH + lane], csr_dis[i], v);
    }
    v *= dn;
    float val = fmaxf(v + b2[lane], 0.0f) * W_lin[lane];
    #pragma unroll
    for (int off = 32; off > 0; off >>= 1) val += __shfl_down(val, off);
    if (lane == 0) out[n] = val + b_lin[0];
}

// ---------------- fallback helpers (atomic scatter path, fp32) ----------------
__global__ void cvt_h2f_kernel(const half_t* __restrict__ in, float* __restrict__ o, size_t n) {
    size_t i = (size_t)blockIdx.x * 256 + threadIdx.x;
    if (i < n) o[i] = (float)in[i];
}

__global__ void agg_init_kernel(const float* __restrict__ xw, const float* __restrict__ dis,
                                float* __restrict__ agg, int nN)
{
    size_t i = (size_t)blockIdx.x * 256 + threadIdx.x;
    if (i >= (size_t)nN * HH) return;
    int n = (int)(i >> 6);
    float d = dis[n];
    agg[i] = xw[i] * d * d;
}

__global__ void scatter_kernel(const float* __restrict__ xw, const float* __restrict__ dis,
                               const int* __restrict__ src, const int* __restrict__ dst,
                               float* __restrict__ agg, int nE, int nN)
{
    const int e = blockIdx.x * 4 + (threadIdx.x >> 6);
    const int lane = threadIdx.x & 63;
    if (e >= nE) return;
    int s = src[e], d = dst[e];
    if ((unsigned)s >= (unsigned)nN || (unsigned)d >= (unsigned)nN) return;
    const float coef = dis[s] * dis[d];
    const float v = xw[(size_t)s * HH + lane] * coef;
    atomicAdd(&agg[(size_t)d * HH + lane], v);
}

template<bool RELU_BIAS, bool WRITE_AGG>
__global__ void xw_kernel(const float* A, const float* __restrict__ W,
                          const float* __restrict__ bias, const float* __restrict__ dis,
                          float* xw_out, float* agg_out, int nN)
{
    const int wave = threadIdx.x >> 6;
    const int lane = threadIdx.x & 63;
    const int n = blockIdx.x * 4 + wave;
    if (n >= nN) return;
    const float* arow = A + (size_t)n * HH;
    float acc = 0.0f;
    #pragma unroll
    for (int k = 0; k < HH; k++) {
        float a = arow[k];
        if (RELU_BIAS) a = fmaxf(a + bias[k], 0.0f);
        acc = fmaf(a, W[k * HH + lane], acc);
    }
    xw_out[(size_t)n * HH + lane] = acc;
    if (WRITE_AGG) {
        const float d = dis[n];
        agg_out[(size_t)n * HH + lane] = acc * d * d;
    }
}

__global__ void head_kernel(const float* __restrict__ agg, const float* __restrict__ b2,
                            const float* __restrict__ W_lin, const float* __restrict__ b_lin,
                            float* __restrict__ out, int nN)
{
    const int wave = threadIdx.x >> 6;
    const int lane = threadIdx.x & 63;
    const int n = blockIdx.x * 4 + wave;
    if (n >= nN) return;
    float v = fmaxf(agg[(size_t)n * HH + lane] + b2[lane], 0.0f) * W_lin[lane];
    #pragma unroll
    for (int off = 32; off > 0; off >>= 1) v += __shfl_down(v, off);
    if (lane == 0) out[n] = v + b_lin[0];
}

extern "C" void kernel_launch(void* const* d_in, const int* in_sizes, int n_in,
                              void* d_out, int out_size, void* d_ws, size_t ws_size,
                              hipStream_t stream)
{
    const float* x     = (const float*)d_in[0];
    const int*   edge  = (const int*)d_in[1];
    const float* W_ih  = (const float*)d_in[2];
    const float* W_hh  = (const float*)d_in[3];
    const float* b_ih  = (const float*)d_in[4];
    const float* b_hh  = (const float*)d_in[5];
    const float* W1    = (const float*)d_in[6];
    const float* b1    = (const float*)d_in[7];
    const float* W2    = (const float*)d_in[8];
    const float* b2    = (const float*)d_in[9];
    const float* W_lin = (const float*)d_in[10];
    const float* b_lin = (const float*)d_in[11];
    float* out = (float*)d_out;

    const int nN = in_sizes[0] / (WW * FF);   // 100000
    const int nE = in_sizes[1] / 2;           // 1600000
    const int* src = edge;
    const int* dst = edge + nE;

    float* ws = (float*)d_ws;
    const size_t npad = ((size_t)nN + 255) & ~(size_t)255;
    float* dis = ws;                           // [N] f32
    float* A   = ws + npad;                    // slot A: [N,64] f32-sized
    float* B   = A + (size_t)nN * HH;          // slot B
    float* C   = B + (size_t)nN * HH;          // slot C
    int*   deg_i   = (int*)(C + (size_t)nN * HH);   // [N]
    int*   row_ptr = deg_i + npad;                  // [N]
    int*   cursor  = row_ptr + npad;                // [N]
    int*   csr_src = cursor + npad;                 // [E]
    float* csr_dis = (float*)(csr_src + nE);        // [E]

    half_t* Bh = (half_t*)B;   // xw1 fp16 (in slot B)
    half_t* Ah = (half_t*)A;   // xw2 fp16 (in slot A)

    const size_t need = (npad + 3 * (size_t)nN * HH + 3 * npad + 2 * (size_t)nE) * 4;
    const bool use_csr = (ws_size >= need);

    const int gN256 = (nN + 255) / 256;
    const int gE256 = (nE + 255) / 256;
    const int gN4   = (nN + 3) / 4;

    if (use_csr) {
        zero_int_kernel<<<gN256, 256, 0, stream>>>(deg_i, nN);
        deg_int_kernel<<<gE256, 256, 0, stream>>>(dst, deg_i, nE, nN);
        dis_from_deg_kernel<<<gN256, 256, 0, stream>>>(deg_i, dis, nN);
        scan_kernel<<<1, 1024, 0, stream>>>(deg_i, row_ptr, cursor, nN);
        place_kernel<<<gE256, 256, 0, stream>>>(src, dst, dis, cursor, csr_src, csr_dis, nE, nN);

        // LSTM + fused xw1 -> Bh (fp16)
        lstm_mfma_kernel<<<(nN + 63) / 64, 256, 0, stream>>>(x, W_ih, W_hh, b_ih, b_hh, W1, Bh, nN);

        // gather1 + fused xw2 -> Ah (fp16) ; gather2 + head -> out
        gather_xw_kernel<<<gN4, 256, 0, stream>>>(Bh, dis, row_ptr, deg_i, csr_src, csr_dis,
                                                  b1, W2, Ah, nN);
        gather_head_kernel<<<gN4, 256, 0, stream>>>(Ah, dis, row_ptr, deg_i, csr_src, csr_dis,
                                                    b2, W_lin, b_lin, out, nN);
    } else {
        zero_int_kernel<<<gN256, 256, 0, stream>>>(deg_i, nN);
        deg_int_kernel<<<gE256, 256, 0, stream>>>(dst, deg_i, nE, nN);
        dis_from_deg_kernel<<<gN256, 256, 0, stream>>>(deg_i, dis, nN);

        lstm_mfma_kernel<<<(nN + 63) / 64, 256, 0, stream>>>(x, W_ih, W_hh, b_ih, b_hh, W1, Bh, nN);

        // fp32 fallback: convert, then atomic-scatter chain (A=xw1f, C=agg1, B=xw2f)
        const size_t NH = (size_t)nN * HH;
        cvt_h2f_kernel<<<(int)((NH + 255) / 256), 256, 0, stream>>>(Bh, A, NH);
        agg_init_kernel<<<(int)((NH + 255) / 256), 256, 0, stream>>>(A, dis, C, nN);
        scatter_kernel<<<(nE + 3) / 4, 256, 0, stream>>>(A, dis, src, dst, C, nE, nN);

        xw_kernel<true, true><<<gN4, 256, 0, stream>>>(C, W2, b1, dis, B, A, nN);
        scatter_kernel<<<(nE + 3) / 4, 256, 0, stream>>>(B, dis, src, dst, A, nE, nN);

        head_kernel<<<gN4, 256, 0, stream>>>(A, b2, W_lin, b_lin, out, nN);
    }
}